// Round 13
// baseline (446.463 us; speedup 1.0000x reference)
//
#include <hip/hip_runtime.h>

#define NN 4096   // H*W
#define DD 256    // feature channels
#define CC 19     // classes
#define BB 2      // batch
#define KSPLIT 4  // split-K factor for new_feat GEMM

typedef __attribute__((ext_vector_type(8))) short bf16x8;     // bf16 MFMA A/B frag
typedef _Float16 f16x8 __attribute__((ext_vector_type(8)));   // fp16 MFMA A/B frag
typedef __attribute__((ext_vector_type(4))) float f32x4;      // MFMA C/D frag

__device__ inline unsigned short f2b(float f) {   // fp32 -> bf16 RNE
  unsigned int u = __float_as_uint(f);
  return (unsigned short)((u + 0x7FFFu + ((u >> 16) & 1u)) >> 16);
}
__device__ inline float b2f(unsigned short h) {
  return __uint_as_float(((unsigned int)h) << 16);
}
__device__ inline unsigned int pack2(float a, float b) {
  return (unsigned int)f2b(a) | ((unsigned int)f2b(b) << 16);
}
// fp32 -> (fp16 hi, fp16 lo*2^11): hi+2^-11*lo carries ~22 mantissa bits
__device__ inline void split16(float x, unsigned short& h, unsigned short& l) {
  _Float16 hh = (_Float16)x;
  float hf = (float)hh;
  _Float16 ll = (_Float16)((x - hf) * 2048.0f);
  h = *reinterpret_cast<unsigned short*>(&hh);
  l = *reinterpret_cast<unsigned short*>(&ll);
}

// ---------------------------------------------------------------------------
// K1: softmax confidence mask + scrambled one-hot bitmasks
// ---------------------------------------------------------------------------
__global__ void k_mask_bits(const float* __restrict__ pred, const float* __restrict__ cw,
                            float* __restrict__ maskb, unsigned int* __restrict__ ohbits) {
  int g = blockIdx.x * 256 + threadIdx.x;
  if (g >= BB * NN) return;
  int b = g >> 12, n = g & (NN - 1);
  const float* p = pred + (size_t)b * CC * NN + n;
  float v[CC];
  float mx = -1e30f; int am = 0;
#pragma unroll
  for (int c = 0; c < CC; ++c) {
    float t = p[(size_t)c * NN];
    v[c] = t;
    if (t > mx) { mx = t; am = c; }
  }
  float s = 0.f;
#pragma unroll
  for (int c = 0; c < CC; ++c) s += expf(v[c] - mx);
  float pprob = 1.f / s;
  float cmax = 0.f;
#pragma unroll
  for (int c = 0; c < CC; ++c) cmax = fmaxf(cmax, cw[c]);
  float cwm = cw[am] / (cmax + 1e-10f) * 0.95f;
  maskb[g] = (pprob >= 0.95f || pprob >= cwm) ? 1.f : 0.f;
  int h = n >> 6, w = n & 63;
  int L = w * (CC * 64) + am * 64 + h;     // flat index in [W,C,H]
  atomicOr(&ohbits[b * NN + L / CC], 1u << (L % CC));
}

// ---------------------------------------------------------------------------
// K2: row-normalize features -> split fp16 hi/lo, stored [b][n][d] (d-major)
// ---------------------------------------------------------------------------
__global__ void k_norm_feat(const float* __restrict__ feat,
                            unsigned short* __restrict__ xh, unsigned short* __restrict__ xl) {
  int g = blockIdx.x * 64 + threadIdx.x;
  int b = g >> 12, n = g & (NN - 1);
  const float* f = feat + (size_t)b * DD * NN + n;
  float s = 0.f;
  for (int d = 0; d < DD; ++d) { float t = f[(size_t)d * NN]; s += t * t; }
  float r = 1.f / (sqrtf(s) + 1e-9f);
  size_t ob = ((size_t)b * NN + n) * DD;
  for (int d = 0; d < DD; d += 4) {
    ushort4 oh, ol;
    split16(f[(size_t)d * NN] * r, oh.x, ol.x);
    split16(f[(size_t)(d + 1) * NN] * r, oh.y, ol.y);
    split16(f[(size_t)(d + 2) * NN] * r, oh.z, ol.z);
    split16(f[(size_t)(d + 3) * NN] * r, oh.w, ol.w);
    *reinterpret_cast<ushort4*>(&xh[ob + d]) = oh;
    *reinterpret_cast<ushort4*>(&xl[ob + d]) = ol;
  }
}

// ---------------------------------------------------------------------------
// K3: aff1 = clamp(Gram(xn), 0) via 3-pass split-fp16 MFMA (~fp32 accuracy).
// fp32 output; LDS-staged epilogue with full-128B-line stores (R11: 132 MB).
// ---------------------------------------------------------------------------
__global__ __launch_bounds__(256, 2) void k_gram1(const unsigned short* __restrict__ xh,
                                                  const unsigned short* __restrict__ xl,
                                                  float* __restrict__ M) {
  int L = blockIdx.x;          // 0..527 triangular (32 tiles/dim)
  int b = blockIdx.y;
  int I = 0;
  while (L >= 32 - I) { L -= 32 - I; ++I; }
  int J = I + L;
  int i0 = I * 128, j0 = J * 128;
  float* Mb = M + (size_t)b * NN * NN;
  const unsigned short* XH = xh + (size_t)b * NN * DD;
  const unsigned short* XL = xl + (size_t)b * NN * DD;
  __shared__ unsigned short stage[4 * 128 * 40];   // 40KB; also reused as float buf
  int t = threadIdx.x;
  int wave = t >> 6, lane = t & 63;
  int wr = (wave & 1) * 64, wc = (wave >> 1) * 64;
  int lrow = lane & 15, quad = lane >> 4;
  f32x4 accH[4][4] = {}, accL[4][4] = {};
  const unsigned short* src = (wave == 0) ? XH + (size_t)i0 * DD
                             : (wave == 1) ? XL + (size_t)i0 * DD
                             : (wave == 2) ? XH + (size_t)j0 * DD
                                           : XL + (size_t)j0 * DD;
  for (int k0 = 0; k0 < DD; k0 += 32) {
#pragma unroll
    for (int e = 0; e < 8; ++e) {
      int row = lane + 64 * (e & 1);
      int o = e >> 1;
      *reinterpret_cast<int4*>(&stage[(wave * 128 + row) * 40 + o * 8]) =
          *reinterpret_cast<const int4*>(&src[(size_t)row * DD + k0 + o * 8]);
    }
    __syncthreads();
    f16x8 ah[4], al[4], bh[4], bl[4];
#pragma unroll
    for (int i = 0; i < 4; ++i) {
      int ra = wr + i * 16 + lrow;
      int rb = wc + i * 16 + lrow;
      ah[i] = *reinterpret_cast<const f16x8*>(&stage[(0 * 128 + ra) * 40 + quad * 8]);
      al[i] = *reinterpret_cast<const f16x8*>(&stage[(1 * 128 + ra) * 40 + quad * 8]);
      bh[i] = *reinterpret_cast<const f16x8*>(&stage[(2 * 128 + rb) * 40 + quad * 8]);
      bl[i] = *reinterpret_cast<const f16x8*>(&stage[(3 * 128 + rb) * 40 + quad * 8]);
    }
#pragma unroll
    for (int i = 0; i < 4; ++i) {
#pragma unroll
      for (int j = 0; j < 4; ++j) {
        accH[i][j] = __builtin_amdgcn_mfma_f32_16x16x32_f16(ah[i], bh[j], accH[i][j], 0, 0, 0);
        accL[i][j] = __builtin_amdgcn_mfma_f32_16x16x32_f16(ah[i], bl[j], accL[i][j], 0, 0, 0);
        accL[i][j] = __builtin_amdgcn_mfma_f32_16x16x32_f16(al[i], bh[j], accL[i][j], 0, 0, 0);
      }
    }
    __syncthreads();
  }
#pragma unroll
  for (int i = 0; i < 4; ++i)
#pragma unroll
    for (int j = 0; j < 4; ++j)
#pragma unroll
      for (int reg = 0; reg < 4; ++reg)
        accH[i][j][reg] = fmaxf(accH[i][j][reg] + accL[i][j][reg] * 4.8828125e-4f, 0.f);
  float* buf = (float*)stage;   // [64][132] floats = 33.8 KB <= 40 KB
  int rr = t >> 4, cc = t & 15;
  for (int half = 0; half < 2; ++half) {
    __syncthreads();
    if ((wr >> 6) == half) {
#pragma unroll
      for (int i = 0; i < 4; ++i)
#pragma unroll
        for (int j = 0; j < 4; ++j)
#pragma unroll
          for (int reg = 0; reg < 4; ++reg)
            buf[(i * 16 + quad * 4 + reg) * 132 + wc + j * 16 + lrow] = accH[i][j][reg];
    }
    __syncthreads();
#pragma unroll
    for (int i = 0; i < 4; ++i) {
      int row = rr + i * 16;
#pragma unroll
      for (int q = 0; q < 2; ++q) {
        int col = cc * 4 + q * 64;
        *reinterpret_cast<float4*>(&Mb[(size_t)(i0 + half * 64 + row) * NN + j0 + col]) =
            *reinterpret_cast<float4*>(&buf[row * 132 + col]);
      }
    }
  }
  if (I != J) {
    for (int half = 0; half < 2; ++half) {
      __syncthreads();
      if ((wc >> 6) == half) {
#pragma unroll
        for (int i = 0; i < 4; ++i)
#pragma unroll
          for (int j = 0; j < 4; ++j)
#pragma unroll
            for (int reg = 0; reg < 4; ++reg)
              buf[(j * 16 + lrow) * 132 + wr + i * 16 + quad * 4 + reg] = accH[i][j][reg];
      }
      __syncthreads();
#pragma unroll
      for (int i = 0; i < 4; ++i) {
        int row = rr + i * 16;
#pragma unroll
        for (int q = 0; q < 2; ++q) {
          int col = cc * 4 + q * 64;
          *reinterpret_cast<float4*>(&Mb[(size_t)(j0 + half * 64 + row) * NN + i0 + col]) =
              *reinterpret_cast<float4*>(&buf[row * 132 + col]);
        }
      }
    }
  }
}

// ---------------------------------------------------------------------------
// K4: per-row 21st-largest via bisection, ONE WAVE PER ROW, row in VGPRs.
// __launch_bounds__(256, 2) grants a 256-VGPR budget so u[64] stays in true
// VGPRs (R12: default budget forced the compiler to shuffle/reload -> 2x
// per-iteration VALU).  Count via ballot+popc; zero barriers/LDS.
// ---------------------------------------------------------------------------
__global__ __launch_bounds__(256, 2) void k_topk(const float* __restrict__ M,
                                                 float* __restrict__ thr) {
  int b = blockIdx.y;
  int wave = threadIdx.x >> 6, lane = threadIdx.x & 63;
  int n = blockIdx.x * 4 + wave;
  const float* row = M + (size_t)b * NN * NN + (size_t)n * NN;
  unsigned int u[64];
#pragma unroll
  for (int e = 0; e < 16; ++e)
    *reinterpret_cast<uint4*>(&u[e * 4]) =
        *reinterpret_cast<const uint4*>(&row[lane * 4 + e * 256]);
  unsigned int lo = 0u, hi = 0x40000000u;   // values in [0, ~1.0+eps]; 2.0f bound
  while (lo < hi) {
    unsigned int mid = lo + ((hi - lo + 1) >> 1);
    int c = 0;
#pragma unroll
    for (int i = 0; i < 64; ++i)
      c += (int)__popcll(__ballot(u[i] >= mid));
    if (c >= 21) lo = mid; else hi = mid - 1;
  }
  if (lane == 0) thr[b * NN + n] = __uint_as_float(lo);
}

// ---------------------------------------------------------------------------
// K5: sparsify + symmetrize.  aff1 is bit-exact symmetric, so
// As[i][j] = a*(1(a>=thr_i) + 1(a>=thr_j)) needs ONLY the (I,J) tile.
// Writes bf16 As packed into each tile's fp32 footprint + degree sums.
// ---------------------------------------------------------------------------
__global__ __launch_bounds__(256) void k_symm(float* __restrict__ M, const float* __restrict__ thr,
                                              float* __restrict__ dsum) {
  int L = blockIdx.x;          // 0..2079 triangular (64 tiles/dim)
  int b = blockIdx.y;
  int I = 0;
  while (L >= 64 - I) { L -= 64 - I; ++I; }
  int J = I + L;
  float* Mb = M + (size_t)b * NN * NN;
  unsigned short* Mus = (unsigned short*)Mb;
  const float* th = thr + b * NN;
  __shared__ float A[64][65];
  int t = threadIdx.x;
  int i0 = I * 64, j0 = J * 64;
  float areg[16];
#pragma unroll
  for (int e = 0; e < 16; ++e) {
    int lin = t + e * 256;
    int i = lin >> 6, j = lin & 63;
    areg[e] = Mb[(size_t)(i0 + i) * NN + j0 + j];
  }
#pragma unroll
  for (int e = 0; e < 16; ++e) {
    int lin = t + e * 256;
    int i = lin >> 6, j = lin & 63;
    float a = areg[e];
    float v = a * ((a >= th[i0 + i] ? 1.f : 0.f) + (a >= th[j0 + j] ? 1.f : 0.f));
    A[i][j] = v;
  }
  __syncthreads();
  {
    int i = t >> 2, seg = (t & 3) * 16;
    float v[16];
#pragma unroll
    for (int q = 0; q < 4; ++q)
      *reinterpret_cast<float4*>(&v[q * 4]) = *reinterpret_cast<float4*>(&A[i][seg + q * 4]);
    unsigned int pk[8];
#pragma unroll
    for (int q = 0; q < 8; ++q) pk[q] = pack2(v[2 * q], v[2 * q + 1]);
    size_t ub = 2 * (size_t)(i0 + i) * NN + 2 * (size_t)j0 + seg;
    *reinterpret_cast<int4*>(&Mus[ub])     = *reinterpret_cast<int4*>(&pk[0]);
    *reinterpret_cast<int4*>(&Mus[ub + 8]) = *reinterpret_cast<int4*>(&pk[4]);
  }
  if (I != J) {   // As is symmetric: mirror footprint gets A^T
    int j = t >> 2, seg = (t & 3) * 16;
    float v[16];
#pragma unroll
    for (int e = 0; e < 16; ++e) v[e] = A[seg + e][j];
    unsigned int pk[8];
#pragma unroll
    for (int q = 0; q < 8; ++q) pk[q] = pack2(v[2 * q], v[2 * q + 1]);
    size_t ub = 2 * (size_t)(j0 + j) * NN + 2 * (size_t)i0 + seg;
    *reinterpret_cast<int4*>(&Mus[ub])     = *reinterpret_cast<int4*>(&pk[0]);
    *reinterpret_cast<int4*>(&Mus[ub + 8]) = *reinterpret_cast<int4*>(&pk[4]);
  }
  if (t < 64) {
    float s = 0.f;
#pragma unroll
    for (int j = 0; j < 64; ++j) s += A[t][j];
    atomicAdd(&dsum[b * NN + i0 + t], s);
  } else if (t < 128 && I != J) {
    int j = t - 64;
    float s = 0.f;
#pragma unroll
    for (int i = 0; i < 64; ++i) s += A[i][j];
    atomicAdd(&dsum[b * NN + j0 + j], s);
  }
}

// ---------------------------------------------------------------------------
// K6: d = (d + 1e-10)^-0.5
// ---------------------------------------------------------------------------
__global__ void k_fin_d(float* __restrict__ d) {
  int g = blockIdx.x * 256 + threadIdx.x;
  if (g < BB * NN) d[g] = 1.f / sqrtf(d[g] + 1e-10f);
}

// ---------------------------------------------------------------------------
// K7: ybh[b][c][n] = bf16(d1[b][n] * pred[b][c][n]), zero-padded to 32 classes
// ---------------------------------------------------------------------------
__global__ void k_make_yb(const float* __restrict__ pred, const float* __restrict__ d1,
                          unsigned short* __restrict__ ybh) {
  int g = blockIdx.x * 256 + threadIdx.x;   // BB*32*NN/4 threads
  int idx = g * 4;
  int b = idx / (32 * NN);
  int c = (idx / NN) & 31;
  int n = idx & (NN - 1);
  ushort4 o = make_ushort4(0, 0, 0, 0);
  if (c < CC) {
    float4 p = *reinterpret_cast<const float4*>(&pred[((size_t)b * CC + c) * NN + n]);
    const float* dd = d1 + b * NN + n;
    o.x = f2b(p.x * dd[0]); o.y = f2b(p.y * dd[1]);
    o.z = f2b(p.z * dd[2]); o.w = f2b(p.w * dd[3]);
  }
  *reinterpret_cast<ushort4*>(&ybh[idx]) = o;
}

// ---------------------------------------------------------------------------
// K8: p2 via MFMA.  GEMM: M=n (64-tile), N=c (32 padded), K=m (4096).
// ---------------------------------------------------------------------------
__global__ __launch_bounds__(256) void k_p2_mfma(
    const float* __restrict__ M, const unsigned short* __restrict__ ybh,
    const float* __restrict__ d1, float* __restrict__ p2b) {
  int b = blockIdx.y;
  int n0 = blockIdx.x * 64;
  const unsigned short* Mus = (const unsigned short*)(M + (size_t)b * NN * NN);
  const unsigned short* Y = ybh + (size_t)b * 32 * NN;
  __shared__ unsigned short As[64][72];
  __shared__ unsigned short Ys[32][72];
  int t = threadIdx.x;
  int wave = t >> 6, lane = t & 63;
  int wn = (wave & 1) * 32;
  int wc = (wave >> 1) * 16;
  int lrow = lane & 15, quad = lane >> 4;
  f32x4 acc[2] = {{0.f,0.f,0.f,0.f},{0.f,0.f,0.f,0.f}};
  int sr = t >> 3, scc = (t & 7) * 8;
  for (int m0 = 0; m0 < NN; m0 += 64) {
#pragma unroll
    for (int e = 0; e < 2; ++e) {
      int rr = sr + e * 32;
      *reinterpret_cast<int4*>(&As[rr][scc]) =
          *reinterpret_cast<const int4*>(&Mus[2 * (size_t)(n0 + rr) * NN + 2 * (size_t)m0 + scc]);
    }
    *reinterpret_cast<int4*>(&Ys[sr][scc]) =
        *reinterpret_cast<const int4*>(&Y[(size_t)sr * NN + m0 + scc]);
    __syncthreads();
#pragma unroll
    for (int kc = 0; kc < 2; ++kc) {
      int ko = kc * 32 + quad * 8;
      bf16x8 bfr = *reinterpret_cast<const bf16x8*>(&Ys[wc + lrow][ko]);
#pragma unroll
      for (int i = 0; i < 2; ++i) {
        bf16x8 af = *reinterpret_cast<const bf16x8*>(&As[wn + i * 16 + lrow][ko]);
        acc[i] = __builtin_amdgcn_mfma_f32_16x16x32_bf16(af, bfr, acc[i], 0, 0, 0);
      }
    }
    __syncthreads();
  }
  int c = wc + lrow;
  if (c < CC) {
#pragma unroll
    for (int i = 0; i < 2; ++i) {
#pragma unroll
      for (int reg = 0; reg < 4; ++reg) {
        int n = n0 + wn + i * 16 + quad * 4 + reg;
        p2b[((size_t)b * NN + n) * CC + c] = d1[b * NN + n] * acc[i][reg];
      }
    }
  }
}

// ---------------------------------------------------------------------------
// K9: fused blend + 19x19 conv x2 -> pred_out, then softmax + cosine-normalize
// ---------------------------------------------------------------------------
__global__ __launch_bounds__(256) void k_pred_head(const float* __restrict__ pred,
    const float* __restrict__ p2b, const float* __restrict__ maskb,
    const float* __restrict__ w1, const float* __restrict__ b1,
    const float* __restrict__ w2, const float* __restrict__ b2,
    float* __restrict__ out, float* __restrict__ spnT) {
  __shared__ float sw1[CC * CC], sw2[CC * CC], sb1[CC], sb2[CC];
  int t = threadIdx.x;
  for (int i = t; i < CC * CC; i += 256) { sw1[i] = w1[i]; sw2[i] = w2[i]; }
  if (t < CC) { sb1[t] = b1[t]; sb2[t] = b2[t]; }
  __syncthreads();
  int g = blockIdx.x * 256 + t;
  int b = g >> 12, n = g & (NN - 1);
  float m = maskb[g];
  float ca = (m > 0.5f) ? 0.2f : 0.8f;
  float cb = (m > 0.5f) ? 0.8f : 0.2f;
  const float* P = pred + (size_t)b * CC * NN + n;
  const float* Q = p2b + (size_t)g * CC;
  float p3[CC];
#pragma unroll
  for (int c = 0; c < CC; ++c) p3[c] = ca * Q[c] + cb * P[(size_t)c * NN];
  float midv[CC];
#pragma unroll
  for (int o = 0; o < CC; ++o) {
    float s = sb1[o];
#pragma unroll
    for (int c = 0; c < CC; ++c) s += sw1[o * CC + c] * p3[c];
    midv[o] = s;
  }
  float ov[CC];
  float mx = -1e30f;
#pragma unroll
  for (int o = 0; o < CC; ++o) {
    float s = sb2[o];
#pragma unroll
    for (int c = 0; c < CC; ++c) s += sw2[o * CC + c] * midv[c];
    ov[o] = s;
    out[(size_t)b * CC * NN + (size_t)o * NN + n] = s;
    mx = fmaxf(mx, s);
  }
  float se = 0.f;
  float e[CC];
#pragma unroll
  for (int o = 0; o < CC; ++o) { e[o] = expf(ov[o] - mx); se += e[o]; }
  float inv = 1.f / se;
  float nrm = 0.f;
#pragma unroll
  for (int o = 0; o < CC; ++o) { float sp = e[o] * inv; e[o] = sp; nrm += sp * sp; }
  float rn = 1.f / (sqrtf(nrm) + 1e-9f);
#pragma unroll
  for (int o = 0; o < CC; ++o) spnT[(size_t)b * CC * NN + (size_t)o * NN + n] = e[o] * rn;
}

// ---------------------------------------------------------------------------
// K10: aff_f = bitmask ? clamp(Gram(spn),0) : 0   (K=19), writes bf16.
// ---------------------------------------------------------------------------
__global__ __launch_bounds__(256) void k_gram2(const float* __restrict__ spnT,
    const unsigned int* __restrict__ bits, unsigned short* __restrict__ Mh) {
  int L = blockIdx.x;          // 0..2079 triangular (64 tiles/dim)
  int b = blockIdx.y;
  int I = 0;
  while (L >= 64 - I) { L -= 64 - I; ++I; }
  int J = I + L;
  const float* X = spnT + (size_t)b * CC * NN;
  unsigned short* Mb = Mh + (size_t)b * NN * NN;
  __shared__ float sA[CC][64], sB[CC][64];
  __shared__ unsigned int bI[64], bJ[64];
  __shared__ float tr[64][65];
  int t = threadIdx.x;
  int r = t >> 4, c = t & 15;
  int i0 = I * 64, j0 = J * 64;
  for (int e = t; e < CC * 64; e += 256) {
    int k = e >> 6, col = e & 63;
    sA[k][col] = X[(size_t)k * NN + i0 + col];
    sB[k][col] = X[(size_t)k * NN + j0 + col];
  }
  if (t < 64) bI[t] = bits[b * NN + i0 + t];
  else if (t < 128) bJ[t - 64] = bits[b * NN + j0 + t - 64];
  __syncthreads();
  float acc[4][4] = {};
#pragma unroll
  for (int k = 0; k < CC; ++k) {
    float av[4], bv[4];
#pragma unroll
    for (int i = 0; i < 4; ++i) av[i] = sA[k][r * 4 + i];
#pragma unroll
    for (int j = 0; j < 4; ++j) bv[j] = sB[k][c * 4 + j];
#pragma unroll
    for (int i = 0; i < 4; ++i) {
#pragma unroll
      for (int j = 0; j < 4; ++j) acc[i][j] += av[i] * bv[j];
    }
  }
#pragma unroll
  for (int i = 0; i < 4; ++i) {
#pragma unroll
    for (int j = 0; j < 4; ++j) {
      bool keep = (bI[r * 4 + i] & bJ[c * 4 + j]) != 0u;
      acc[i][j] = keep ? fmaxf(acc[i][j], 0.f) : 0.f;
    }
    ushort4 v;
    v.x = f2b(acc[i][0]); v.y = f2b(acc[i][1]); v.z = f2b(acc[i][2]); v.w = f2b(acc[i][3]);
    *reinterpret_cast<ushort4*>(&Mb[(size_t)(i0 + r * 4 + i) * NN + j0 + c * 4]) = v;
  }
  if (I != J) {
#pragma unroll
    for (int i = 0; i < 4; ++i) {
#pragma unroll
      for (int j = 0; j < 4; ++j) tr[r * 4 + i][c * 4 + j] = acc[i][j];
    }
    __syncthreads();
#pragma unroll
    for (int e = 0; e < 16; ++e) {
      int lin = t + e * 256;
      int jr = lin >> 6, ic = lin & 63;
      Mb[(size_t)(j0 + jr) * NN + i0 + ic] = f2b(tr[ic][jr]);
    }
  }
}

// ---------------------------------------------------------------------------
// K11: d2[n] = (row_sum(aff_f bf16) + 1e-10)^-0.5
// ---------------------------------------------------------------------------
__global__ __launch_bounds__(256) void k_rowsum2h(const unsigned short* __restrict__ Mh,
                                                  float* __restrict__ d2) {
  int b = blockIdx.y, n = blockIdx.x;
  const unsigned short* row = Mh + (size_t)b * NN * NN + (size_t)n * NN;
  int t = threadIdx.x;
  float s = 0.f;
#pragma unroll
  for (int i = 0; i < 8; ++i) {
    unsigned int u = *reinterpret_cast<const unsigned int*>(&row[(i * 256 + t) * 2]);
    s += __uint_as_float(u << 16) + __uint_as_float(u & 0xffff0000u);
  }
  for (int off = 32; off > 0; off >>= 1) s += __shfl_down(s, off);
  __shared__ float p4[4];
  int wid = t >> 6, lane = t & 63;
  if (lane == 0) p4[wid] = s;
  __syncthreads();
  if (t == 0) d2[b * NN + n] = 1.f / sqrtf(p4[0] + p4[1] + p4[2] + p4[3] + 1e-10f);
}

// ---------------------------------------------------------------------------
// K12a: zb[b][d][m] = bf16(feat[b][d][m] * d2[b][m])
// ---------------------------------------------------------------------------
__global__ void k_make_z(const float* __restrict__ feat, const float* __restrict__ d2,
                         unsigned short* __restrict__ zb) {
  int g = blockIdx.x * 256 + threadIdx.x;   // BB*DD*NN/4 threads
  int idx = g * 4;
  int b = idx / (DD * NN);
  int m = idx & (NN - 1);
  float4 f = *reinterpret_cast<const float4*>(&feat[idx]);
  const float* dd = d2 + b * NN + m;
  ushort4 o;
  o.x = f2b(f.x * dd[0]); o.y = f2b(f.y * dd[1]);
  o.z = f2b(f.z * dd[2]); o.w = f2b(f.w * dd[3]);
  *reinterpret_cast<ushort4*>(&zb[idx]) = o;
}

// K12b: convert projection weights to bf16
__global__ void k_prep_w(const float* __restrict__ w1, const float* __restrict__ w2,
                         unsigned short* __restrict__ wb1, unsigned short* __restrict__ wb2) {
  int g = blockIdx.x * 256 + threadIdx.x;   // DD*DD threads
  wb1[g] = f2b(w1[g]);
  wb2[g] = f2b(w2[g]);
}

// ---------------------------------------------------------------------------
// K13: new_feat via MFMA with split-K x4.  GEMM: M=d(64), N=n(64), K=1024.
// ---------------------------------------------------------------------------
__global__ __launch_bounds__(256) void k_newfeat_mfma(
    const unsigned short* __restrict__ Mh, const unsigned short* __restrict__ zb,
    float* __restrict__ nfp) {
  int zz = blockIdx.z;                 // b*KSPLIT + ks
  int b = zz / KSPLIT, ks = zz % KSPLIT;
  int nblk = blockIdx.x;   // 64
  int dblk = blockIdx.y;   // 4
  const int KLEN = NN / KSPLIT;        // 1024
  const unsigned short* A = zb + (size_t)b * DD * NN + (size_t)(dblk * 64) * NN + ks * KLEN;
  const unsigned short* Bm = Mh + (size_t)b * NN * NN + (size_t)(nblk * 64) * NN + ks * KLEN;
  __shared__ unsigned short As[64][72];
  __shared__ unsigned short Bs[64][72];
  int t = threadIdx.x;
  int wave = t >> 6, lane = t & 63;
  int wd = (wave & 1) * 32, wn = (wave >> 1) * 32;
  int lrow = lane & 15, quad = lane >> 4;
  f32x4 acc[2][2] = {{{0.f,0.f,0.f,0.f},{0.f,0.f,0.f,0.f}},{{0.f,0.f,0.f,0.f},{0.f,0.f,0.f,0.f}}};
  int sr = t >> 3, sc = (t & 7) * 8;
  for (int m0 = 0; m0 < KLEN; m0 += 64) {
#pragma unroll
    for (int e = 0; e < 2; ++e) {
      int rr = sr + e * 32;
      *reinterpret_cast<int4*>(&As[rr][sc]) =
          *reinterpret_cast<const int4*>(&A[(size_t)rr * NN + m0 + sc]);
      *reinterpret_cast<int4*>(&Bs[rr][sc]) =
          *reinterpret_cast<const int4*>(&Bm[(size_t)rr * NN + m0 + sc]);
    }
    __syncthreads();
#pragma unroll
    for (int kc = 0; kc < 2; ++kc) {
      int ko = kc * 32 + quad * 8;
      bf16x8 af[2], bfr[2];
#pragma unroll
      for (int i = 0; i < 2; ++i) {
        af[i]  = *reinterpret_cast<const bf16x8*>(&As[wd + i * 16 + lrow][ko]);
        bfr[i] = *reinterpret_cast<const bf16x8*>(&Bs[wn + i * 16 + lrow][ko]);
      }
#pragma unroll
      for (int i = 0; i < 2; ++i)
#pragma unroll
        for (int j = 0; j < 2; ++j)
          acc[i][j] = __builtin_amdgcn_mfma_f32_16x16x32_bf16(af[i], bfr[j], acc[i][j], 0, 0, 0);
    }
    __syncthreads();
  }
#pragma unroll
  for (int j = 0; j < 2; ++j) {
    int n = nblk * 64 + wn + j * 16 + lrow;
#pragma unroll
    for (int i = 0; i < 2; ++i) {
      int d = dblk * 64 + wd + i * 16 + quad * 4;
      float4 v = make_float4(acc[i][j].x, acc[i][j].y, acc[i][j].z, acc[i][j].w);
      *reinterpret_cast<float4*>(&nfp[((size_t)zz * NN + n) * DD + d]) = v;
    }
  }
}

// ---------------------------------------------------------------------------
// K13b: reduce split-K partials, scale by d2, emit bf16 nfh[b][n][d]
// ---------------------------------------------------------------------------
__global__ void k_nf_reduce(const float* __restrict__ nfp, const float* __restrict__ d2,
                            unsigned short* __restrict__ nfh) {
  int g = blockIdx.x * 256 + threadIdx.x;   // BB*NN*DD/4 threads
  int idx = g * 4;
  int b = idx / (NN * DD);
  int n = (idx / DD) & (NN - 1);
  size_t base = (size_t)idx + (size_t)b * (KSPLIT - 1) * NN * DD;
  float4 s = make_float4(0.f, 0.f, 0.f, 0.f);
#pragma unroll
  for (int ks = 0; ks < KSPLIT; ++ks) {
    float4 v = *reinterpret_cast<const float4*>(&nfp[base + (size_t)ks * NN * DD]);
    s.x += v.x; s.y += v.y; s.z += v.z; s.w += v.w;
  }
  float sc = d2[b * NN + n];
  ushort4 o;
  o.x = f2b(s.x * sc); o.y = f2b(s.y * sc); o.z = f2b(s.z * sc); o.w = f2b(s.w * sc);
  *reinterpret_cast<ushort4*>(&nfh[idx]) = o;
}

// ---------------------------------------------------------------------------
// K14: conv1 via MFMA. GEMM: M=n, N=o1, K=d.
// ---------------------------------------------------------------------------
__global__ __launch_bounds__(256) void k_conv1_mfma(
    const unsigned short* __restrict__ nfh, const unsigned short* __restrict__ wb1,
    const float* __restrict__ b1, unsigned short* __restrict__ midh) {
  int b = blockIdx.z;
  int nblk = blockIdx.x;   // 64
  int oblk = blockIdx.y;   // 4
  int n0 = nblk * 64, o0 = oblk * 64;
  __shared__ unsigned short As[64][72];
  __shared__ unsigned short Bs[64][72];
  int t = threadIdx.x;
  int wave = t >> 6, lane = t & 63;
  int wn = (wave & 1) * 32, wo = (wave >> 1) * 32;
  int lrow = lane & 15, quad = lane >> 4;
  f32x4 acc[2][2] = {{{0.f,0.f,0.f,0.f},{0.f,0.f,0.f,0.f}},{{0.f,0.f,0.f,0.f},{0.f,0.f,0.f,0.f}}};
  int sr = t >> 3, sc = (t & 7) * 8;
  for (int d0 = 0; d0 < DD; d0 += 64) {
#pragma unroll
    for (int e = 0; e < 2; ++e) {
      int rr = sr + e * 32;
      *reinterpret_cast<int4*>(&As[rr][sc]) =
          *reinterpret_cast<const int4*>(&nfh[((size_t)b * NN + n0 + rr) * DD + d0 + sc]);
      *reinterpret_cast<int4*>(&Bs[rr][sc]) =
          *reinterpret_cast<const int4*>(&wb1[(size_t)(o0 + rr) * DD + d0 + sc]);
    }
    __syncthreads();
#pragma unroll
    for (int kc = 0; kc < 2; ++kc) {
      int ko = kc * 32 + quad * 8;
      bf16x8 af[2], bfr[2];
#pragma unroll
      for (int i = 0; i < 2; ++i) {
        af[i]  = *reinterpret_cast<const bf16x8*>(&As[wn + i * 16 + lrow][ko]);
        bfr[i] = *reinterpret_cast<const bf16x8*>(&Bs[wo + i * 16 + lrow][ko]);
      }
#pragma unroll
      for (int i = 0; i < 2; ++i)
#pragma unroll
        for (int j = 0; j < 2; ++j)
          acc[i][j] = __builtin_amdgcn_mfma_f32_16x16x32_bf16(af[i], bfr[j], acc[i][j], 0, 0, 0);
    }
    __syncthreads();
  }
#pragma unroll
  for (int j = 0; j < 2; ++j) {
    int o = o0 + wo + j * 16 + lrow;
    float bias = b1[o];
#pragma unroll
    for (int i = 0; i < 2; ++i) {
      int nb = n0 + wn + i * 16 + quad * 4;
      ushort4 v;
      v.x = f2b(fmaxf(acc[i][j].x + bias, 0.f));
      v.y = f2b(fmaxf(acc[i][j].y + bias, 0.f));
      v.z = f2b(fmaxf(acc[i][j].z + bias, 0.f));
      v.w = f2b(fmaxf(acc[i][j].w + bias, 0.f));
      *reinterpret_cast<ushort4*>(&midh[((size_t)b * DD + o) * NN + nb]) = v;
    }
  }
}

// ---------------------------------------------------------------------------
// K15: conv2 via MFMA. GEMM: M=n, N=o2, K=o1.
// ---------------------------------------------------------------------------
__global__ __launch_bounds__(256) void k_conv2_mfma(
    const unsigned short* __restrict__ midh, const unsigned short* __restrict__ wb2,
    const float* __restrict__ b2, float* __restrict__ outp) {
  int b = blockIdx.z;
  int nblk = blockIdx.x;   // 64
  int oblk = blockIdx.y;   // 4
  int n0 = nblk * 64, o0 = oblk * 64;
  __shared__ unsigned short As[64][72];
  __shared__ unsigned short Bs[64][72];
  int t = threadIdx.x;
  int wave = t >> 6, lane = t & 63;
  int wn = (wave & 1) * 32, wo = (wave >> 1) * 32;
  int lrow = lane & 15, quad = lane >> 4;
  f32x4 acc[2][2] = {{{0.f,0.f,0.f,0.f},{0.f,0.f,0.f,0.f}},{{0.f,0.f,0.f,0.f},{0.f,0.f,0.f,0.f}}};
  int sr = t >> 3, sc = (t & 7) * 8;
  for (int d0 = 0; d0 < DD; d0 += 64) {
#pragma unroll
    for (int e = 0; e < 2; ++e) {
      int rr = sr + e * 32;
      *reinterpret_cast<int4*>(&Bs[rr][sc]) =
          *reinterpret_cast<const int4*>(&wb2[(size_t)(o0 + rr) * DD + d0 + sc]);
      unsigned short v[8];
      *reinterpret_cast<int4*>(v) =
          *reinterpret_cast<const int4*>(&midh[((size_t)b * DD + d0 + rr) * NN + n0 + sc]);
#pragma unroll
      for (int j = 0; j < 8; ++j) As[sc + j][rr] = v[j];
    }
    __syncthreads();
#pragma unroll
    for (int kc = 0; kc < 2; ++kc) {
      int ko = kc * 32 + quad * 8;
      bf16x8 af[2], bfr[2];
#pragma unroll
      for (int i = 0; i < 2; ++i) {
        af[i]  = *reinterpret_cast<const bf16x8*>(&As[wn + i * 16 + lrow][ko]);
        bfr[i] = *reinterpret_cast<const bf16x8*>(&Bs[wo + i * 16 + lrow][ko]);
      }
#pragma unroll
      for (int i = 0; i < 2; ++i)
#pragma unroll
        for (int j = 0; j < 2; ++j)
          acc[i][j] = __builtin_amdgcn_mfma_f32_16x16x32_bf16(af[i], bfr[j], acc[i][j], 0, 0, 0);
    }
    __syncthreads();
  }
#pragma unroll
  for (int j = 0; j < 2; ++j) {
    int o = o0 + wo + j * 16 + lrow;
    float bias = b2[o];
#pragma unroll
    for (int i = 0; i < 2; ++i) {
      int nb = n0 + wn + i * 16 + quad * 4;
      float4 v = make_float4(acc[i][j].x + bias, acc[i][j].y + bias,
                             acc[i][j].z + bias, acc[i][j].w + bias);
      *reinterpret_cast<float4*>(&outp[((size_t)b * DD + o) * NN + nb]) = v;
    }
  }
}

// ---------------------------------------------------------------------------
extern "C" void kernel_launch(void* const* d_in, const int* in_sizes, int n_in,
                              void* d_out, int out_size, void* d_ws, size_t ws_size,
                              hipStream_t stream) {
  (void)in_sizes; (void)n_in; (void)out_size; (void)ws_size;
  const float* pred   = (const float*)d_in[0];
  const float* feat   = (const float*)d_in[1];
  const float* w_cls1 = (const float*)d_in[2];
  const float* b_cls1 = (const float*)d_in[3];
  const float* w_cls2 = (const float*)d_in[4];
  const float* b_cls2 = (const float*)d_in[5];
  const float* w_pro1 = (const float*)d_in[6];
  const float* b_pro1 = (const float*)d_in[7];
  const float* w_pro2 = (const float*)d_in[8];
  const float* b_pro2 = (const float*)d_in[9];
  const float* cw     = (const float*)d_in[10];
  float* out = (float*)d_out;

  // workspace layout
  float* Mbuf = (float*)d_ws;                               // B*N*N fp32 (aff1 / packed-bf16 As / bf16 aff_f)
  float* spnT = Mbuf + (size_t)BB * NN * NN;
  float* p2b  = spnT + (size_t)BB * CC * NN;
  float* thr  = p2b + (size_t)BB * NN * CC;
  float* dsum = thr + BB * NN;
  float* d2s  = dsum + BB * NN;
  float* maskb = d2s + BB * NN;
  unsigned int* ohbits = (unsigned int*)(maskb + BB * NN);
  unsigned short* xh   = (unsigned short*)(ohbits + BB * NN);  // B*N*D fp16 hi
  unsigned short* xl   = xh + (size_t)BB * NN * DD;            // B*N*D fp16 lo*2^11
  unsigned short* nfh  = xl + (size_t)BB * NN * DD;            // B*N*D bf16
  unsigned short* midh = nfh + (size_t)BB * NN * DD;           // B*D*N bf16
  unsigned short* zb   = midh + (size_t)BB * DD * NN;          // B*D*N bf16
  unsigned short* wb1  = zb + (size_t)BB * DD * NN;            // D*D bf16
  unsigned short* wb2  = wb1 + (size_t)DD * DD;                // D*D bf16
  unsigned short* ybh  = wb2 + (size_t)DD * DD;                // B*32*N bf16 (padded y)
  unsigned short* Mh   = (unsigned short*)Mbuf;
  // split-K partials alias the upper half of Mbuf (dead after k_p2)
  float* nfp = (float*)(Mh + (size_t)BB * NN * NN);            // KSPLIT*B*N*D fp32 = 32 MB

  hipMemsetAsync(dsum, 0, sizeof(float) * BB * NN, stream);
  hipMemsetAsync(ohbits, 0, sizeof(unsigned int) * BB * NN, stream);

  // --- pred branch ---
  k_mask_bits<<<BB * NN / 256, 256, 0, stream>>>(pred, cw, maskb, ohbits);
  k_norm_feat<<<BB * NN / 64, 64, 0, stream>>>(feat, xh, xl);
  k_gram1<<<dim3(528, BB), 256, 0, stream>>>(xh, xl, Mbuf);
  k_topk<<<dim3(NN / 4, BB), 256, 0, stream>>>(Mbuf, thr);
  k_symm<<<dim3(2080, BB), 256, 0, stream>>>(Mbuf, thr, dsum);
  k_fin_d<<<BB * NN / 256, 256, 0, stream>>>(dsum);
  k_make_yb<<<BB * 32 * NN / 4 / 256, 256, 0, stream>>>(pred, dsum, ybh);
  k_p2_mfma<<<dim3(NN / 64, BB), 256, 0, stream>>>(Mbuf, ybh, dsum, p2b);
  k_pred_head<<<BB * NN / 256, 256, 0, stream>>>(pred, p2b, maskb, w_cls1, b_cls1,
                                                 w_cls2, b_cls2, out, spnT);
  // --- feat branch (bf16 MFMA) ---
  k_gram2<<<dim3(2080, BB), 256, 0, stream>>>(spnT, ohbits, Mh);
  k_rowsum2h<<<dim3(NN, BB), 256, 0, stream>>>(Mh, d2s);
  k_make_z<<<BB * DD * NN / 4 / 256, 256, 0, stream>>>(feat, d2s, zb);
  k_prep_w<<<DD * DD / 256, 256, 0, stream>>>(w_pro1, w_pro2, wb1, wb2);
  k_newfeat_mfma<<<dim3(64, 4, BB * KSPLIT), 256, 0, stream>>>(Mh, zb, nfp);
  k_nf_reduce<<<BB * NN * DD / 4 / 256, 256, 0, stream>>>(nfp, d2s, nfh);
  k_conv1_mfma<<<dim3(64, 4, BB), 256, 0, stream>>>(nfh, wb1, b_pro1, midh);
  k_conv2_mfma<<<dim3(64, 4, BB), 256, 0, stream>>>(midh, wb2, b_pro2,
                                                    out + (size_t)BB * CC * NN);
}

// Round 14
// 443.938 us; speedup vs baseline: 1.0057x; 1.0057x over previous
//
#include <hip/hip_runtime.h>

#define NN 4096   // H*W
#define DD 256    // feature channels
#define CC 19     // classes
#define BB 2      // batch
#define KSPLIT 4  // split-K factor for new_feat GEMM

typedef __attribute__((ext_vector_type(8))) short bf16x8;     // bf16 MFMA A/B frag
typedef _Float16 f16x8 __attribute__((ext_vector_type(8)));   // fp16 MFMA A/B frag
typedef __attribute__((ext_vector_type(4))) float f32x4;      // MFMA C/D frag

__device__ inline unsigned short f2b(float f) {   // fp32 -> bf16 RNE
  unsigned int u = __float_as_uint(f);
  return (unsigned short)((u + 0x7FFFu + ((u >> 16) & 1u)) >> 16);
}
__device__ inline float b2f(unsigned short h) {
  return __uint_as_float(((unsigned int)h) << 16);
}
__device__ inline unsigned int pack2(float a, float b) {
  return (unsigned int)f2b(a) | ((unsigned int)f2b(b) << 16);
}
// fp32 -> (fp16 hi, fp16 lo*2^11): hi+2^-11*lo carries ~22 mantissa bits
__device__ inline void split16(float x, unsigned short& h, unsigned short& l) {
  _Float16 hh = (_Float16)x;
  float hf = (float)hh;
  _Float16 ll = (_Float16)((x - hf) * 2048.0f);
  h = *reinterpret_cast<unsigned short*>(&hh);
  l = *reinterpret_cast<unsigned short*>(&ll);
}

// ---------------------------------------------------------------------------
// K1: softmax confidence mask + scrambled one-hot bitmasks
// ---------------------------------------------------------------------------
__global__ void k_mask_bits(const float* __restrict__ pred, const float* __restrict__ cw,
                            float* __restrict__ maskb, unsigned int* __restrict__ ohbits) {
  int g = blockIdx.x * 256 + threadIdx.x;
  if (g >= BB * NN) return;
  int b = g >> 12, n = g & (NN - 1);
  const float* p = pred + (size_t)b * CC * NN + n;
  float v[CC];
  float mx = -1e30f; int am = 0;
#pragma unroll
  for (int c = 0; c < CC; ++c) {
    float t = p[(size_t)c * NN];
    v[c] = t;
    if (t > mx) { mx = t; am = c; }
  }
  float s = 0.f;
#pragma unroll
  for (int c = 0; c < CC; ++c) s += expf(v[c] - mx);
  float pprob = 1.f / s;
  float cmax = 0.f;
#pragma unroll
  for (int c = 0; c < CC; ++c) cmax = fmaxf(cmax, cw[c]);
  float cwm = cw[am] / (cmax + 1e-10f) * 0.95f;
  maskb[g] = (pprob >= 0.95f || pprob >= cwm) ? 1.f : 0.f;
  int h = n >> 6, w = n & 63;
  int L = w * (CC * 64) + am * 64 + h;     // flat index in [W,C,H]
  atomicOr(&ohbits[b * NN + L / CC], 1u << (L % CC));
}

// ---------------------------------------------------------------------------
// K2: row-normalize features -> split fp16 hi/lo, stored [b][n][d] (d-major)
// ---------------------------------------------------------------------------
__global__ void k_norm_feat(const float* __restrict__ feat,
                            unsigned short* __restrict__ xh, unsigned short* __restrict__ xl) {
  int g = blockIdx.x * 64 + threadIdx.x;
  int b = g >> 12, n = g & (NN - 1);
  const float* f = feat + (size_t)b * DD * NN + n;
  float s = 0.f;
  for (int d = 0; d < DD; ++d) { float t = f[(size_t)d * NN]; s += t * t; }
  float r = 1.f / (sqrtf(s) + 1e-9f);
  size_t ob = ((size_t)b * NN + n) * DD;
  for (int d = 0; d < DD; d += 4) {
    ushort4 oh, ol;
    split16(f[(size_t)d * NN] * r, oh.x, ol.x);
    split16(f[(size_t)(d + 1) * NN] * r, oh.y, ol.y);
    split16(f[(size_t)(d + 2) * NN] * r, oh.z, ol.z);
    split16(f[(size_t)(d + 3) * NN] * r, oh.w, ol.w);
    *reinterpret_cast<ushort4*>(&xh[ob + d]) = oh;
    *reinterpret_cast<ushort4*>(&xl[ob + d]) = ol;
  }
}

// ---------------------------------------------------------------------------
// K3: aff1 = clamp(Gram(xn), 0) via 3-pass split-fp16 MFMA (~fp32 accuracy).
// fp32 output; LDS-staged epilogue with full-128B-line stores (R11: 132 MB).
// ---------------------------------------------------------------------------
__global__ __launch_bounds__(256, 2) void k_gram1(const unsigned short* __restrict__ xh,
                                                  const unsigned short* __restrict__ xl,
                                                  float* __restrict__ M) {
  int L = blockIdx.x;          // 0..527 triangular (32 tiles/dim)
  int b = blockIdx.y;
  int I = 0;
  while (L >= 32 - I) { L -= 32 - I; ++I; }
  int J = I + L;
  int i0 = I * 128, j0 = J * 128;
  float* Mb = M + (size_t)b * NN * NN;
  const unsigned short* XH = xh + (size_t)b * NN * DD;
  const unsigned short* XL = xl + (size_t)b * NN * DD;
  __shared__ unsigned short stage[4 * 128 * 40];   // 40KB; also reused as float buf
  int t = threadIdx.x;
  int wave = t >> 6, lane = t & 63;
  int wr = (wave & 1) * 64, wc = (wave >> 1) * 64;
  int lrow = lane & 15, quad = lane >> 4;
  f32x4 accH[4][4] = {}, accL[4][4] = {};
  const unsigned short* src = (wave == 0) ? XH + (size_t)i0 * DD
                             : (wave == 1) ? XL + (size_t)i0 * DD
                             : (wave == 2) ? XH + (size_t)j0 * DD
                                           : XL + (size_t)j0 * DD;
  for (int k0 = 0; k0 < DD; k0 += 32) {
#pragma unroll
    for (int e = 0; e < 8; ++e) {
      int row = lane + 64 * (e & 1);
      int o = e >> 1;
      *reinterpret_cast<int4*>(&stage[(wave * 128 + row) * 40 + o * 8]) =
          *reinterpret_cast<const int4*>(&src[(size_t)row * DD + k0 + o * 8]);
    }
    __syncthreads();
    f16x8 ah[4], al[4], bh[4], bl[4];
#pragma unroll
    for (int i = 0; i < 4; ++i) {
      int ra = wr + i * 16 + lrow;
      int rb = wc + i * 16 + lrow;
      ah[i] = *reinterpret_cast<const f16x8*>(&stage[(0 * 128 + ra) * 40 + quad * 8]);
      al[i] = *reinterpret_cast<const f16x8*>(&stage[(1 * 128 + ra) * 40 + quad * 8]);
      bh[i] = *reinterpret_cast<const f16x8*>(&stage[(2 * 128 + rb) * 40 + quad * 8]);
      bl[i] = *reinterpret_cast<const f16x8*>(&stage[(3 * 128 + rb) * 40 + quad * 8]);
    }
#pragma unroll
    for (int i = 0; i < 4; ++i) {
#pragma unroll
      for (int j = 0; j < 4; ++j) {
        accH[i][j] = __builtin_amdgcn_mfma_f32_16x16x32_f16(ah[i], bh[j], accH[i][j], 0, 0, 0);
        accL[i][j] = __builtin_amdgcn_mfma_f32_16x16x32_f16(ah[i], bl[j], accL[i][j], 0, 0, 0);
        accL[i][j] = __builtin_amdgcn_mfma_f32_16x16x32_f16(al[i], bh[j], accL[i][j], 0, 0, 0);
      }
    }
    __syncthreads();
  }
#pragma unroll
  for (int i = 0; i < 4; ++i)
#pragma unroll
    for (int j = 0; j < 4; ++j)
#pragma unroll
      for (int reg = 0; reg < 4; ++reg)
        accH[i][j][reg] = fmaxf(accH[i][j][reg] + accL[i][j][reg] * 4.8828125e-4f, 0.f);
  float* buf = (float*)stage;   // [64][132] floats = 33.8 KB <= 40 KB
  int rr = t >> 4, cc = t & 15;
  for (int half = 0; half < 2; ++half) {
    __syncthreads();
    if ((wr >> 6) == half) {
#pragma unroll
      for (int i = 0; i < 4; ++i)
#pragma unroll
        for (int j = 0; j < 4; ++j)
#pragma unroll
          for (int reg = 0; reg < 4; ++reg)
            buf[(i * 16 + quad * 4 + reg) * 132 + wc + j * 16 + lrow] = accH[i][j][reg];
    }
    __syncthreads();
#pragma unroll
    for (int i = 0; i < 4; ++i) {
      int row = rr + i * 16;
#pragma unroll
      for (int q = 0; q < 2; ++q) {
        int col = cc * 4 + q * 64;
        *reinterpret_cast<float4*>(&Mb[(size_t)(i0 + half * 64 + row) * NN + j0 + col]) =
            *reinterpret_cast<float4*>(&buf[row * 132 + col]);
      }
    }
  }
  if (I != J) {
    for (int half = 0; half < 2; ++half) {
      __syncthreads();
      if ((wc >> 6) == half) {
#pragma unroll
        for (int i = 0; i < 4; ++i)
#pragma unroll
          for (int j = 0; j < 4; ++j)
#pragma unroll
            for (int reg = 0; reg < 4; ++reg)
              buf[(j * 16 + lrow) * 132 + wr + i * 16 + quad * 4 + reg] = accH[i][j][reg];
      }
      __syncthreads();
#pragma unroll
      for (int i = 0; i < 4; ++i) {
        int row = rr + i * 16;
#pragma unroll
        for (int q = 0; q < 2; ++q) {
          int col = cc * 4 + q * 64;
          *reinterpret_cast<float4*>(&Mb[(size_t)(j0 + half * 64 + row) * NN + i0 + col]) =
              *reinterpret_cast<float4*>(&buf[row * 132 + col]);
        }
      }
    }
  }
}

// ---------------------------------------------------------------------------
// K4: per-row 21st-largest via bisection, ONE WAVE PER ROW, row in VGPRs.
// R13 post-mortem: the compiler SANK the loads into the bisection loop
// (re-reading 2 GB from L2; VGPR stayed 40).  The empty inline-asm "+v"
// constraint makes each loaded value opaque -> it must stay in a VGPR and
// cannot be rematerialized.  Count via ballot+popc (SALU, dual-issued).
// ---------------------------------------------------------------------------
__global__ __launch_bounds__(256, 2) void k_topk(const float* __restrict__ M,
                                                 float* __restrict__ thr) {
  int b = blockIdx.y;
  int wave = threadIdx.x >> 6, lane = threadIdx.x & 63;
  int n = blockIdx.x * 4 + wave;
  const float* row = M + (size_t)b * NN * NN + (size_t)n * NN;
  unsigned int u[64];
#pragma unroll
  for (int e = 0; e < 16; ++e)
    *reinterpret_cast<uint4*>(&u[e * 4]) =
        *reinterpret_cast<const uint4*>(&row[lane * 4 + e * 256]);
#pragma unroll
  for (int i = 0; i < 64; ++i) asm volatile("" : "+v"(u[i]));   // pin to VGPRs
  unsigned int lo = 0u, hi = 0x40000000u;   // values in [0, ~1.0+eps]; 2.0f bound
  while (lo < hi) {
    unsigned int mid = lo + ((hi - lo + 1) >> 1);
    int c = 0;
#pragma unroll
    for (int i = 0; i < 64; ++i)
      c += (int)__popcll(__ballot(u[i] >= mid));
    if (c >= 21) lo = mid; else hi = mid - 1;
  }
  if (lane == 0) thr[b * NN + n] = __uint_as_float(lo);
}

// ---------------------------------------------------------------------------
// K5: sparsify + symmetrize.  aff1 is bit-exact symmetric, so
// As[i][j] = a*(1(a>=thr_i) + 1(a>=thr_j)) needs ONLY the (I,J) tile.
// Writes bf16 As packed into each tile's fp32 footprint + degree sums.
// ---------------------------------------------------------------------------
__global__ __launch_bounds__(256) void k_symm(float* __restrict__ M, const float* __restrict__ thr,
                                              float* __restrict__ dsum) {
  int L = blockIdx.x;          // 0..2079 triangular (64 tiles/dim)
  int b = blockIdx.y;
  int I = 0;
  while (L >= 64 - I) { L -= 64 - I; ++I; }
  int J = I + L;
  float* Mb = M + (size_t)b * NN * NN;
  unsigned short* Mus = (unsigned short*)Mb;
  const float* th = thr + b * NN;
  __shared__ float A[64][65];
  int t = threadIdx.x;
  int i0 = I * 64, j0 = J * 64;
  float areg[16];
#pragma unroll
  for (int e = 0; e < 16; ++e) {
    int lin = t + e * 256;
    int i = lin >> 6, j = lin & 63;
    areg[e] = Mb[(size_t)(i0 + i) * NN + j0 + j];
  }
#pragma unroll
  for (int e = 0; e < 16; ++e) {
    int lin = t + e * 256;
    int i = lin >> 6, j = lin & 63;
    float a = areg[e];
    float v = a * ((a >= th[i0 + i] ? 1.f : 0.f) + (a >= th[j0 + j] ? 1.f : 0.f));
    A[i][j] = v;
  }
  __syncthreads();
  {
    int i = t >> 2, seg = (t & 3) * 16;
    float v[16];
#pragma unroll
    for (int q = 0; q < 4; ++q)
      *reinterpret_cast<float4*>(&v[q * 4]) = *reinterpret_cast<float4*>(&A[i][seg + q * 4]);
    unsigned int pk[8];
#pragma unroll
    for (int q = 0; q < 8; ++q) pk[q] = pack2(v[2 * q], v[2 * q + 1]);
    size_t ub = 2 * (size_t)(i0 + i) * NN + 2 * (size_t)j0 + seg;
    *reinterpret_cast<int4*>(&Mus[ub])     = *reinterpret_cast<int4*>(&pk[0]);
    *reinterpret_cast<int4*>(&Mus[ub + 8]) = *reinterpret_cast<int4*>(&pk[4]);
  }
  if (I != J) {   // As is symmetric: mirror footprint gets A^T
    int j = t >> 2, seg = (t & 3) * 16;
    float v[16];
#pragma unroll
    for (int e = 0; e < 16; ++e) v[e] = A[seg + e][j];
    unsigned int pk[8];
#pragma unroll
    for (int q = 0; q < 8; ++q) pk[q] = pack2(v[2 * q], v[2 * q + 1]);
    size_t ub = 2 * (size_t)(j0 + j) * NN + 2 * (size_t)i0 + seg;
    *reinterpret_cast<int4*>(&Mus[ub])     = *reinterpret_cast<int4*>(&pk[0]);
    *reinterpret_cast<int4*>(&Mus[ub + 8]) = *reinterpret_cast<int4*>(&pk[4]);
  }
  if (t < 64) {
    float s = 0.f;
#pragma unroll
    for (int j = 0; j < 64; ++j) s += A[t][j];
    atomicAdd(&dsum[b * NN + i0 + t], s);
  } else if (t < 128 && I != J) {
    int j = t - 64;
    float s = 0.f;
#pragma unroll
    for (int i = 0; i < 64; ++i) s += A[i][j];
    atomicAdd(&dsum[b * NN + j0 + j], s);
  }
}

// ---------------------------------------------------------------------------
// K6: d = (d + 1e-10)^-0.5
// ---------------------------------------------------------------------------
__global__ void k_fin_d(float* __restrict__ d) {
  int g = blockIdx.x * 256 + threadIdx.x;
  if (g < BB * NN) d[g] = 1.f / sqrtf(d[g] + 1e-10f);
}

// ---------------------------------------------------------------------------
// K7: ybh[b][c][n] = bf16(d1[b][n] * pred[b][c][n]), zero-padded to 32 classes
// ---------------------------------------------------------------------------
__global__ void k_make_yb(const float* __restrict__ pred, const float* __restrict__ d1,
                          unsigned short* __restrict__ ybh) {
  int g = blockIdx.x * 256 + threadIdx.x;   // BB*32*NN/4 threads
  int idx = g * 4;
  int b = idx / (32 * NN);
  int c = (idx / NN) & 31;
  int n = idx & (NN - 1);
  ushort4 o = make_ushort4(0, 0, 0, 0);
  if (c < CC) {
    float4 p = *reinterpret_cast<const float4*>(&pred[((size_t)b * CC + c) * NN + n]);
    const float* dd = d1 + b * NN + n;
    o.x = f2b(p.x * dd[0]); o.y = f2b(p.y * dd[1]);
    o.z = f2b(p.z * dd[2]); o.w = f2b(p.w * dd[3]);
  }
  *reinterpret_cast<ushort4*>(&ybh[idx]) = o;
}

// ---------------------------------------------------------------------------
// K8: p2 via MFMA.  GEMM: M=n (64-tile), N=c (32 padded), K=m (4096).
// ---------------------------------------------------------------------------
__global__ __launch_bounds__(256) void k_p2_mfma(
    const float* __restrict__ M, const unsigned short* __restrict__ ybh,
    const float* __restrict__ d1, float* __restrict__ p2b) {
  int b = blockIdx.y;
  int n0 = blockIdx.x * 64;
  const unsigned short* Mus = (const unsigned short*)(M + (size_t)b * NN * NN);
  const unsigned short* Y = ybh + (size_t)b * 32 * NN;
  __shared__ unsigned short As[64][72];
  __shared__ unsigned short Ys[32][72];
  int t = threadIdx.x;
  int wave = t >> 6, lane = t & 63;
  int wn = (wave & 1) * 32;
  int wc = (wave >> 1) * 16;
  int lrow = lane & 15, quad = lane >> 4;
  f32x4 acc[2] = {{0.f,0.f,0.f,0.f},{0.f,0.f,0.f,0.f}};
  int sr = t >> 3, scc = (t & 7) * 8;
  for (int m0 = 0; m0 < NN; m0 += 64) {
#pragma unroll
    for (int e = 0; e < 2; ++e) {
      int rr = sr + e * 32;
      *reinterpret_cast<int4*>(&As[rr][scc]) =
          *reinterpret_cast<const int4*>(&Mus[2 * (size_t)(n0 + rr) * NN + 2 * (size_t)m0 + scc]);
    }
    *reinterpret_cast<int4*>(&Ys[sr][scc]) =
        *reinterpret_cast<const int4*>(&Y[(size_t)sr * NN + m0 + scc]);
    __syncthreads();
#pragma unroll
    for (int kc = 0; kc < 2; ++kc) {
      int ko = kc * 32 + quad * 8;
      bf16x8 bfr = *reinterpret_cast<const bf16x8*>(&Ys[wc + lrow][ko]);
#pragma unroll
      for (int i = 0; i < 2; ++i) {
        bf16x8 af = *reinterpret_cast<const bf16x8*>(&As[wn + i * 16 + lrow][ko]);
        acc[i] = __builtin_amdgcn_mfma_f32_16x16x32_bf16(af, bfr, acc[i], 0, 0, 0);
      }
    }
    __syncthreads();
  }
  int c = wc + lrow;
  if (c < CC) {
#pragma unroll
    for (int i = 0; i < 2; ++i) {
#pragma unroll
      for (int reg = 0; reg < 4; ++reg) {
        int n = n0 + wn + i * 16 + quad * 4 + reg;
        p2b[((size_t)b * NN + n) * CC + c] = d1[b * NN + n] * acc[i][reg];
      }
    }
  }
}

// ---------------------------------------------------------------------------
// K9: fused blend + 19x19 conv x2 -> pred_out, then softmax + cosine-normalize
// ---------------------------------------------------------------------------
__global__ __launch_bounds__(256) void k_pred_head(const float* __restrict__ pred,
    const float* __restrict__ p2b, const float* __restrict__ maskb,
    const float* __restrict__ w1, const float* __restrict__ b1,
    const float* __restrict__ w2, const float* __restrict__ b2,
    float* __restrict__ out, float* __restrict__ spnT) {
  __shared__ float sw1[CC * CC], sw2[CC * CC], sb1[CC], sb2[CC];
  int t = threadIdx.x;
  for (int i = t; i < CC * CC; i += 256) { sw1[i] = w1[i]; sw2[i] = w2[i]; }
  if (t < CC) { sb1[t] = b1[t]; sb2[t] = b2[t]; }
  __syncthreads();
  int g = blockIdx.x * 256 + t;
  int b = g >> 12, n = g & (NN - 1);
  float m = maskb[g];
  float ca = (m > 0.5f) ? 0.2f : 0.8f;
  float cb = (m > 0.5f) ? 0.8f : 0.2f;
  const float* P = pred + (size_t)b * CC * NN + n;
  const float* Q = p2b + (size_t)g * CC;
  float p3[CC];
#pragma unroll
  for (int c = 0; c < CC; ++c) p3[c] = ca * Q[c] + cb * P[(size_t)c * NN];
  float midv[CC];
#pragma unroll
  for (int o = 0; o < CC; ++o) {
    float s = sb1[o];
#pragma unroll
    for (int c = 0; c < CC; ++c) s += sw1[o * CC + c] * p3[c];
    midv[o] = s;
  }
  float ov[CC];
  float mx = -1e30f;
#pragma unroll
  for (int o = 0; o < CC; ++o) {
    float s = sb2[o];
#pragma unroll
    for (int c = 0; c < CC; ++c) s += sw2[o * CC + c] * midv[c];
    ov[o] = s;
    out[(size_t)b * CC * NN + (size_t)o * NN + n] = s;
    mx = fmaxf(mx, s);
  }
  float se = 0.f;
  float e[CC];
#pragma unroll
  for (int o = 0; o < CC; ++o) { e[o] = expf(ov[o] - mx); se += e[o]; }
  float inv = 1.f / se;
  float nrm = 0.f;
#pragma unroll
  for (int o = 0; o < CC; ++o) { float sp = e[o] * inv; e[o] = sp; nrm += sp * sp; }
  float rn = 1.f / (sqrtf(nrm) + 1e-9f);
#pragma unroll
  for (int o = 0; o < CC; ++o) spnT[(size_t)b * CC * NN + (size_t)o * NN + n] = e[o] * rn;
}

// ---------------------------------------------------------------------------
// K10: aff_f = bitmask ? clamp(Gram(spn),0) : 0   (K=19), writes bf16.
// ---------------------------------------------------------------------------
__global__ __launch_bounds__(256) void k_gram2(const float* __restrict__ spnT,
    const unsigned int* __restrict__ bits, unsigned short* __restrict__ Mh) {
  int L = blockIdx.x;          // 0..2079 triangular (64 tiles/dim)
  int b = blockIdx.y;
  int I = 0;
  while (L >= 64 - I) { L -= 64 - I; ++I; }
  int J = I + L;
  const float* X = spnT + (size_t)b * CC * NN;
  unsigned short* Mb = Mh + (size_t)b * NN * NN;
  __shared__ float sA[CC][64], sB[CC][64];
  __shared__ unsigned int bI[64], bJ[64];
  __shared__ float tr[64][65];
  int t = threadIdx.x;
  int r = t >> 4, c = t & 15;
  int i0 = I * 64, j0 = J * 64;
  for (int e = t; e < CC * 64; e += 256) {
    int k = e >> 6, col = e & 63;
    sA[k][col] = X[(size_t)k * NN + i0 + col];
    sB[k][col] = X[(size_t)k * NN + j0 + col];
  }
  if (t < 64) bI[t] = bits[b * NN + i0 + t];
  else if (t < 128) bJ[t - 64] = bits[b * NN + j0 + t - 64];
  __syncthreads();
  float acc[4][4] = {};
#pragma unroll
  for (int k = 0; k < CC; ++k) {
    float av[4], bv[4];
#pragma unroll
    for (int i = 0; i < 4; ++i) av[i] = sA[k][r * 4 + i];
#pragma unroll
    for (int j = 0; j < 4; ++j) bv[j] = sB[k][c * 4 + j];
#pragma unroll
    for (int i = 0; i < 4; ++i) {
#pragma unroll
      for (int j = 0; j < 4; ++j) acc[i][j] += av[i] * bv[j];
    }
  }
#pragma unroll
  for (int i = 0; i < 4; ++i) {
#pragma unroll
    for (int j = 0; j < 4; ++j) {
      bool keep = (bI[r * 4 + i] & bJ[c * 4 + j]) != 0u;
      acc[i][j] = keep ? fmaxf(acc[i][j], 0.f) : 0.f;
    }
    ushort4 v;
    v.x = f2b(acc[i][0]); v.y = f2b(acc[i][1]); v.z = f2b(acc[i][2]); v.w = f2b(acc[i][3]);
    *reinterpret_cast<ushort4*>(&Mb[(size_t)(i0 + r * 4 + i) * NN + j0 + c * 4]) = v;
  }
  if (I != J) {
#pragma unroll
    for (int i = 0; i < 4; ++i) {
#pragma unroll
      for (int j = 0; j < 4; ++j) tr[r * 4 + i][c * 4 + j] = acc[i][j];
    }
    __syncthreads();
#pragma unroll
    for (int e = 0; e < 16; ++e) {
      int lin = t + e * 256;
      int jr = lin >> 6, ic = lin & 63;
      Mb[(size_t)(j0 + jr) * NN + i0 + ic] = f2b(tr[ic][jr]);
    }
  }
}

// ---------------------------------------------------------------------------
// K11: d2[n] = (row_sum(aff_f bf16) + 1e-10)^-0.5
// ---------------------------------------------------------------------------
__global__ __launch_bounds__(256) void k_rowsum2h(const unsigned short* __restrict__ Mh,
                                                  float* __restrict__ d2) {
  int b = blockIdx.y, n = blockIdx.x;
  const unsigned short* row = Mh + (size_t)b * NN * NN + (size_t)n * NN;
  int t = threadIdx.x;
  float s = 0.f;
#pragma unroll
  for (int i = 0; i < 8; ++i) {
    unsigned int u = *reinterpret_cast<const unsigned int*>(&row[(i * 256 + t) * 2]);
    s += __uint_as_float(u << 16) + __uint_as_float(u & 0xffff0000u);
  }
  for (int off = 32; off > 0; off >>= 1) s += __shfl_down(s, off);
  __shared__ float p4[4];
  int wid = t >> 6, lane = t & 63;
  if (lane == 0) p4[wid] = s;
  __syncthreads();
  if (t == 0) d2[b * NN + n] = 1.f / sqrtf(p4[0] + p4[1] + p4[2] + p4[3] + 1e-10f);
}

// ---------------------------------------------------------------------------
// K12a: zb[b][d][m] = bf16(feat[b][d][m] * d2[b][m])
// ---------------------------------------------------------------------------
__global__ void k_make_z(const float* __restrict__ feat, const float* __restrict__ d2,
                         unsigned short* __restrict__ zb) {
  int g = blockIdx.x * 256 + threadIdx.x;   // BB*DD*NN/4 threads
  int idx = g * 4;
  int b = idx / (DD * NN);
  int m = idx & (NN - 1);
  float4 f = *reinterpret_cast<const float4*>(&feat[idx]);
  const float* dd = d2 + b * NN + m;
  ushort4 o;
  o.x = f2b(f.x * dd[0]); o.y = f2b(f.y * dd[1]);
  o.z = f2b(f.z * dd[2]); o.w = f2b(f.w * dd[3]);
  *reinterpret_cast<ushort4*>(&zb[idx]) = o;
}

// K12b: convert projection weights to bf16
__global__ void k_prep_w(const float* __restrict__ w1, const float* __restrict__ w2,
                         unsigned short* __restrict__ wb1, unsigned short* __restrict__ wb2) {
  int g = blockIdx.x * 256 + threadIdx.x;   // DD*DD threads
  wb1[g] = f2b(w1[g]);
  wb2[g] = f2b(w2[g]);
}

// ---------------------------------------------------------------------------
// K13: new_feat via MFMA with split-K x4.  GEMM: M=d(64), N=n(64), K=1024.
// ---------------------------------------------------------------------------
__global__ __launch_bounds__(256) void k_newfeat_mfma(
    const unsigned short* __restrict__ Mh, const unsigned short* __restrict__ zb,
    float* __restrict__ nfp) {
  int zz = blockIdx.z;                 // b*KSPLIT + ks
  int b = zz / KSPLIT, ks = zz % KSPLIT;
  int nblk = blockIdx.x;   // 64
  int dblk = blockIdx.y;   // 4
  const int KLEN = NN / KSPLIT;        // 1024
  const unsigned short* A = zb + (size_t)b * DD * NN + (size_t)(dblk * 64) * NN + ks * KLEN;
  const unsigned short* Bm = Mh + (size_t)b * NN * NN + (size_t)(nblk * 64) * NN + ks * KLEN;
  __shared__ unsigned short As[64][72];
  __shared__ unsigned short Bs[64][72];
  int t = threadIdx.x;
  int wave = t >> 6, lane = t & 63;
  int wd = (wave & 1) * 32, wn = (wave >> 1) * 32;
  int lrow = lane & 15, quad = lane >> 4;
  f32x4 acc[2][2] = {{{0.f,0.f,0.f,0.f},{0.f,0.f,0.f,0.f}},{{0.f,0.f,0.f,0.f},{0.f,0.f,0.f,0.f}}};
  int sr = t >> 3, sc = (t & 7) * 8;
  for (int m0 = 0; m0 < KLEN; m0 += 64) {
#pragma unroll
    for (int e = 0; e < 2; ++e) {
      int rr = sr + e * 32;
      *reinterpret_cast<int4*>(&As[rr][sc]) =
          *reinterpret_cast<const int4*>(&A[(size_t)rr * NN + m0 + sc]);
      *reinterpret_cast<int4*>(&Bs[rr][sc]) =
          *reinterpret_cast<const int4*>(&Bm[(size_t)rr * NN + m0 + sc]);
    }
    __syncthreads();
#pragma unroll
    for (int kc = 0; kc < 2; ++kc) {
      int ko = kc * 32 + quad * 8;
      bf16x8 af[2], bfr[2];
#pragma unroll
      for (int i = 0; i < 2; ++i) {
        af[i]  = *reinterpret_cast<const bf16x8*>(&As[wd + i * 16 + lrow][ko]);
        bfr[i] = *reinterpret_cast<const bf16x8*>(&Bs[wn + i * 16 + lrow][ko]);
      }
#pragma unroll
      for (int i = 0; i < 2; ++i)
#pragma unroll
        for (int j = 0; j < 2; ++j)
          acc[i][j] = __builtin_amdgcn_mfma_f32_16x16x32_bf16(af[i], bfr[j], acc[i][j], 0, 0, 0);
    }
    __syncthreads();
  }
#pragma unroll
  for (int j = 0; j < 2; ++j) {
    int n = nblk * 64 + wn + j * 16 + lrow;
#pragma unroll
    for (int i = 0; i < 2; ++i) {
      int d = dblk * 64 + wd + i * 16 + quad * 4;
      float4 v = make_float4(acc[i][j].x, acc[i][j].y, acc[i][j].z, acc[i][j].w);
      *reinterpret_cast<float4*>(&nfp[((size_t)zz * NN + n) * DD + d]) = v;
    }
  }
}

// ---------------------------------------------------------------------------
// K13b: reduce split-K partials, scale by d2, emit bf16 nfh[b][n][d]
// ---------------------------------------------------------------------------
__global__ void k_nf_reduce(const float* __restrict__ nfp, const float* __restrict__ d2,
                            unsigned short* __restrict__ nfh) {
  int g = blockIdx.x * 256 + threadIdx.x;   // BB*NN*DD/4 threads
  int idx = g * 4;
  int b = idx / (NN * DD);
  int n = (idx / DD) & (NN - 1);
  size_t base = (size_t)idx + (size_t)b * (KSPLIT - 1) * NN * DD;
  float4 s = make_float4(0.f, 0.f, 0.f, 0.f);
#pragma unroll
  for (int ks = 0; ks < KSPLIT; ++ks) {
    float4 v = *reinterpret_cast<const float4*>(&nfp[base + (size_t)ks * NN * DD]);
    s.x += v.x; s.y += v.y; s.z += v.z; s.w += v.w;
  }
  float sc = d2[b * NN + n];
  ushort4 o;
  o.x = f2b(s.x * sc); o.y = f2b(s.y * sc); o.z = f2b(s.z * sc); o.w = f2b(s.w * sc);
  *reinterpret_cast<ushort4*>(&nfh[idx]) = o;
}

// ---------------------------------------------------------------------------
// K14: conv1 via MFMA. GEMM: M=n, N=o1, K=d.
// ---------------------------------------------------------------------------
__global__ __launch_bounds__(256) void k_conv1_mfma(
    const unsigned short* __restrict__ nfh, const unsigned short* __restrict__ wb1,
    const float* __restrict__ b1, unsigned short* __restrict__ midh) {
  int b = blockIdx.z;
  int nblk = blockIdx.x;   // 64
  int oblk = blockIdx.y;   // 4
  int n0 = nblk * 64, o0 = oblk * 64;
  __shared__ unsigned short As[64][72];
  __shared__ unsigned short Bs[64][72];
  int t = threadIdx.x;
  int wave = t >> 6, lane = t & 63;
  int wn = (wave & 1) * 32, wo = (wave >> 1) * 32;
  int lrow = lane & 15, quad = lane >> 4;
  f32x4 acc[2][2] = {{{0.f,0.f,0.f,0.f},{0.f,0.f,0.f,0.f}},{{0.f,0.f,0.f,0.f},{0.f,0.f,0.f,0.f}}};
  int sr = t >> 3, sc = (t & 7) * 8;
  for (int d0 = 0; d0 < DD; d0 += 64) {
#pragma unroll
    for (int e = 0; e < 2; ++e) {
      int rr = sr + e * 32;
      *reinterpret_cast<int4*>(&As[rr][sc]) =
          *reinterpret_cast<const int4*>(&nfh[((size_t)b * NN + n0 + rr) * DD + d0 + sc]);
      *reinterpret_cast<int4*>(&Bs[rr][sc]) =
          *reinterpret_cast<const int4*>(&wb1[(size_t)(o0 + rr) * DD + d0 + sc]);
    }
    __syncthreads();
#pragma unroll
    for (int kc = 0; kc < 2; ++kc) {
      int ko = kc * 32 + quad * 8;
      bf16x8 af[2], bfr[2];
#pragma unroll
      for (int i = 0; i < 2; ++i) {
        af[i]  = *reinterpret_cast<const bf16x8*>(&As[wn + i * 16 + lrow][ko]);
        bfr[i] = *reinterpret_cast<const bf16x8*>(&Bs[wo + i * 16 + lrow][ko]);
      }
#pragma unroll
      for (int i = 0; i < 2; ++i)
#pragma unroll
        for (int j = 0; j < 2; ++j)
          acc[i][j] = __builtin_amdgcn_mfma_f32_16x16x32_bf16(af[i], bfr[j], acc[i][j], 0, 0, 0);
    }
    __syncthreads();
  }
#pragma unroll
  for (int j = 0; j < 2; ++j) {
    int o = o0 + wo + j * 16 + lrow;
    float bias = b1[o];
#pragma unroll
    for (int i = 0; i < 2; ++i) {
      int nb = n0 + wn + i * 16 + quad * 4;
      ushort4 v;
      v.x = f2b(fmaxf(acc[i][j].x + bias, 0.f));
      v.y = f2b(fmaxf(acc[i][j].y + bias, 0.f));
      v.z = f2b(fmaxf(acc[i][j].z + bias, 0.f));
      v.w = f2b(fmaxf(acc[i][j].w + bias, 0.f));
      *reinterpret_cast<ushort4*>(&midh[((size_t)b * DD + o) * NN + nb]) = v;
    }
  }
}

// ---------------------------------------------------------------------------
// K15: conv2 via MFMA. GEMM: M=n, N=o2, K=o1.
// ---------------------------------------------------------------------------
__global__ __launch_bounds__(256) void k_conv2_mfma(
    const unsigned short* __restrict__ midh, const unsigned short* __restrict__ wb2,
    const float* __restrict__ b2, float* __restrict__ outp) {
  int b = blockIdx.z;
  int nblk = blockIdx.x;   // 64
  int oblk = blockIdx.y;   // 4
  int n0 = nblk * 64, o0 = oblk * 64;
  __shared__ unsigned short As[64][72];
  __shared__ unsigned short Bs[64][72];
  int t = threadIdx.x;
  int wave = t >> 6, lane = t & 63;
  int wn = (wave & 1) * 32, wo = (wave >> 1) * 32;
  int lrow = lane & 15, quad = lane >> 4;
  f32x4 acc[2][2] = {{{0.f,0.f,0.f,0.f},{0.f,0.f,0.f,0.f}},{{0.f,0.f,0.f,0.f},{0.f,0.f,0.f,0.f}}};
  int sr = t >> 3, sc = (t & 7) * 8;
  for (int d0 = 0; d0 < DD; d0 += 64) {
#pragma unroll
    for (int e = 0; e < 2; ++e) {
      int rr = sr + e * 32;
      *reinterpret_cast<int4*>(&Bs[rr][sc]) =
          *reinterpret_cast<const int4*>(&wb2[(size_t)(o0 + rr) * DD + d0 + sc]);
      unsigned short v[8];
      *reinterpret_cast<int4*>(v) =
          *reinterpret_cast<const int4*>(&midh[((size_t)b * DD + d0 + rr) * NN + n0 + sc]);
#pragma unroll
      for (int j = 0; j < 8; ++j) As[sc + j][rr] = v[j];
    }
    __syncthreads();
#pragma unroll
    for (int kc = 0; kc < 2; ++kc) {
      int ko = kc * 32 + quad * 8;
      bf16x8 af[2], bfr[2];
#pragma unroll
      for (int i = 0; i < 2; ++i) {
        af[i]  = *reinterpret_cast<const bf16x8*>(&As[wn + i * 16 + lrow][ko]);
        bfr[i] = *reinterpret_cast<const bf16x8*>(&Bs[wo + i * 16 + lrow][ko]);
      }
#pragma unroll
      for (int i = 0; i < 2; ++i)
#pragma unroll
        for (int j = 0; j < 2; ++j)
          acc[i][j] = __builtin_amdgcn_mfma_f32_16x16x32_bf16(af[i], bfr[j], acc[i][j], 0, 0, 0);
    }
    __syncthreads();
  }
#pragma unroll
  for (int j = 0; j < 2; ++j) {
    int o = o0 + wo + j * 16 + lrow;
    float bias = b2[o];
#pragma unroll
    for (int i = 0; i < 2; ++i) {
      int nb = n0 + wn + i * 16 + quad * 4;
      float4 v = make_float4(acc[i][j].x + bias, acc[i][j].y + bias,
                             acc[i][j].z + bias, acc[i][j].w + bias);
      *reinterpret_cast<float4*>(&outp[((size_t)b * DD + o) * NN + nb]) = v;
    }
  }
}

// ---------------------------------------------------------------------------
extern "C" void kernel_launch(void* const* d_in, const int* in_sizes, int n_in,
                              void* d_out, int out_size, void* d_ws, size_t ws_size,
                              hipStream_t stream) {
  (void)in_sizes; (void)n_in; (void)out_size; (void)ws_size;
  const float* pred   = (const float*)d_in[0];
  const float* feat   = (const float*)d_in[1];
  const float* w_cls1 = (const float*)d_in[2];
  const float* b_cls1 = (const float*)d_in[3];
  const float* w_cls2 = (const float*)d_in[4];
  const float* b_cls2 = (const float*)d_in[5];
  const float* w_pro1 = (const float*)d_in[6];
  const float* b_pro1 = (const float*)d_in[7];
  const float* w_pro2 = (const float*)d_in[8];
  const float* b_pro2 = (const float*)d_in[9];
  const float* cw     = (const float*)d_in[10];
  float* out = (float*)d_out;

  // workspace layout
  float* Mbuf = (float*)d_ws;                               // B*N*N fp32 (aff1 / packed-bf16 As / bf16 aff_f)
  float* spnT = Mbuf + (size_t)BB * NN * NN;
  float* p2b  = spnT + (size_t)BB * CC * NN;
  float* thr  = p2b + (size_t)BB * NN * CC;
  float* dsum = thr + BB * NN;
  float* d2s  = dsum + BB * NN;
  float* maskb = d2s + BB * NN;
  unsigned int* ohbits = (unsigned int*)(maskb + BB * NN);
  unsigned short* xh   = (unsigned short*)(ohbits + BB * NN);  // B*N*D fp16 hi
  unsigned short* xl   = xh + (size_t)BB * NN * DD;            // B*N*D fp16 lo*2^11
  unsigned short* nfh  = xl + (size_t)BB * NN * DD;            // B*N*D bf16
  unsigned short* midh = nfh + (size_t)BB * NN * DD;           // B*D*N bf16
  unsigned short* zb   = midh + (size_t)BB * DD * NN;          // B*D*N bf16
  unsigned short* wb1  = zb + (size_t)BB * DD * NN;            // D*D bf16
  unsigned short* wb2  = wb1 + (size_t)DD * DD;                // D*D bf16
  unsigned short* ybh  = wb2 + (size_t)DD * DD;                // B*32*N bf16 (padded y)
  unsigned short* Mh   = (unsigned short*)Mbuf;
  // split-K partials alias the upper half of Mbuf (dead after k_p2)
  float* nfp = (float*)(Mh + (size_t)BB * NN * NN);            // KSPLIT*B*N*D fp32 = 32 MB

  hipMemsetAsync(dsum, 0, sizeof(float) * BB * NN, stream);
  hipMemsetAsync(ohbits, 0, sizeof(unsigned int) * BB * NN, stream);

  // --- pred branch ---
  k_mask_bits<<<BB * NN / 256, 256, 0, stream>>>(pred, cw, maskb, ohbits);
  k_norm_feat<<<BB * NN / 64, 64, 0, stream>>>(feat, xh, xl);
  k_gram1<<<dim3(528, BB), 256, 0, stream>>>(xh, xl, Mbuf);
  k_topk<<<dim3(NN / 4, BB), 256, 0, stream>>>(Mbuf, thr);
  k_symm<<<dim3(2080, BB), 256, 0, stream>>>(Mbuf, thr, dsum);
  k_fin_d<<<BB * NN / 256, 256, 0, stream>>>(dsum);
  k_make_yb<<<BB * 32 * NN / 4 / 256, 256, 0, stream>>>(pred, dsum, ybh);
  k_p2_mfma<<<dim3(NN / 64, BB), 256, 0, stream>>>(Mbuf, ybh, dsum, p2b);
  k_pred_head<<<BB * NN / 256, 256, 0, stream>>>(pred, p2b, maskb, w_cls1, b_cls1,
                                                 w_cls2, b_cls2, out, spnT);
  // --- feat branch (bf16 MFMA) ---
  k_gram2<<<dim3(2080, BB), 256, 0, stream>>>(spnT, ohbits, Mh);
  k_rowsum2h<<<dim3(NN, BB), 256, 0, stream>>>(Mh, d2s);
  k_make_z<<<BB * DD * NN / 4 / 256, 256, 0, stream>>>(feat, d2s, zb);
  k_prep_w<<<DD * DD / 256, 256, 0, stream>>>(w_pro1, w_pro2, wb1, wb2);
  k_newfeat_mfma<<<dim3(64, 4, BB * KSPLIT), 256, 0, stream>>>(Mh, zb, nfp);
  k_nf_reduce<<<BB * NN * DD / 4 / 256, 256, 0, stream>>>(nfp, d2s, nfh);
  k_conv1_mfma<<<dim3(64, 4, BB), 256, 0, stream>>>(nfh, wb1, b_pro1, midh);
  k_conv2_mfma<<<dim3(64, 4, BB), 256, 0, stream>>>(midh, wb2, b_pro2,
                                                    out + (size_t)BB * CC * NN);
}

// Round 15
// 443.052 us; speedup vs baseline: 1.0077x; 1.0020x over previous
//
#include <hip/hip_runtime.h>

#define NN 4096   // H*W
#define DD 256    // feature channels
#define CC 19     // classes
#define BB 2      // batch
#define KSPLIT 4  // split-K factor for new_feat GEMM

typedef __attribute__((ext_vector_type(8))) short bf16x8;     // bf16 MFMA A/B frag
typedef _Float16 f16x8 __attribute__((ext_vector_type(8)));   // fp16 MFMA A/B frag
typedef __attribute__((ext_vector_type(4))) float f32x4;      // MFMA C/D frag

__device__ inline unsigned short f2b(float f) {   // fp32 -> bf16 RNE
  unsigned int u = __float_as_uint(f);
  return (unsigned short)((u + 0x7FFFu + ((u >> 16) & 1u)) >> 16);
}
__device__ inline float b2f(unsigned short h) {
  return __uint_as_float(((unsigned int)h) << 16);
}
__device__ inline unsigned int pack2(float a, float b) {
  return (unsigned int)f2b(a) | ((unsigned int)f2b(b) << 16);
}
// fp32 -> (fp16 hi, fp16 lo*2^11): hi+2^-11*lo carries ~22 mantissa bits
__device__ inline void split16(float x, unsigned short& h, unsigned short& l) {
  _Float16 hh = (_Float16)x;
  float hf = (float)hh;
  _Float16 ll = (_Float16)((x - hf) * 2048.0f);
  h = *reinterpret_cast<unsigned short*>(&hh);
  l = *reinterpret_cast<unsigned short*>(&ll);
}

// ---------------------------------------------------------------------------
// K1: softmax confidence mask + scrambled one-hot bitmasks
// ---------------------------------------------------------------------------
__global__ void k_mask_bits(const float* __restrict__ pred, const float* __restrict__ cw,
                            float* __restrict__ maskb, unsigned int* __restrict__ ohbits) {
  int g = blockIdx.x * 256 + threadIdx.x;
  if (g >= BB * NN) return;
  int b = g >> 12, n = g & (NN - 1);
  const float* p = pred + (size_t)b * CC * NN + n;
  float v[CC];
  float mx = -1e30f; int am = 0;
#pragma unroll
  for (int c = 0; c < CC; ++c) {
    float t = p[(size_t)c * NN];
    v[c] = t;
    if (t > mx) { mx = t; am = c; }
  }
  float s = 0.f;
#pragma unroll
  for (int c = 0; c < CC; ++c) s += expf(v[c] - mx);
  float pprob = 1.f / s;
  float cmax = 0.f;
#pragma unroll
  for (int c = 0; c < CC; ++c) cmax = fmaxf(cmax, cw[c]);
  float cwm = cw[am] / (cmax + 1e-10f) * 0.95f;
  maskb[g] = (pprob >= 0.95f || pprob >= cwm) ? 1.f : 0.f;
  int h = n >> 6, w = n & 63;
  int L = w * (CC * 64) + am * 64 + h;     // flat index in [W,C,H]
  atomicOr(&ohbits[b * NN + L / CC], 1u << (L % CC));
}

// ---------------------------------------------------------------------------
// K2: row-normalize features -> split fp16 hi/lo, stored [b][n][d] (d-major)
// ---------------------------------------------------------------------------
__global__ void k_norm_feat(const float* __restrict__ feat,
                            unsigned short* __restrict__ xh, unsigned short* __restrict__ xl) {
  int g = blockIdx.x * 64 + threadIdx.x;
  int b = g >> 12, n = g & (NN - 1);
  const float* f = feat + (size_t)b * DD * NN + n;
  float s = 0.f;
  for (int d = 0; d < DD; ++d) { float t = f[(size_t)d * NN]; s += t * t; }
  float r = 1.f / (sqrtf(s) + 1e-9f);
  size_t ob = ((size_t)b * NN + n) * DD;
  for (int d = 0; d < DD; d += 4) {
    ushort4 oh, ol;
    split16(f[(size_t)d * NN] * r, oh.x, ol.x);
    split16(f[(size_t)(d + 1) * NN] * r, oh.y, ol.y);
    split16(f[(size_t)(d + 2) * NN] * r, oh.z, ol.z);
    split16(f[(size_t)(d + 3) * NN] * r, oh.w, ol.w);
    *reinterpret_cast<ushort4*>(&xh[ob + d]) = oh;
    *reinterpret_cast<ushort4*>(&xl[ob + d]) = ol;
  }
}

// ---------------------------------------------------------------------------
// K3: aff1 = clamp(Gram(xn), 0) via 3-pass split-fp16 MFMA (~fp32 accuracy).
// fp32 output; LDS-staged epilogue with full-128B-line stores (R11: 132 MB).
// ---------------------------------------------------------------------------
__global__ __launch_bounds__(256, 2) void k_gram1(const unsigned short* __restrict__ xh,
                                                  const unsigned short* __restrict__ xl,
                                                  float* __restrict__ M) {
  int L = blockIdx.x;          // 0..527 triangular (32 tiles/dim)
  int b = blockIdx.y;
  int I = 0;
  while (L >= 32 - I) { L -= 32 - I; ++I; }
  int J = I + L;
  int i0 = I * 128, j0 = J * 128;
  float* Mb = M + (size_t)b * NN * NN;
  const unsigned short* XH = xh + (size_t)b * NN * DD;
  const unsigned short* XL = xl + (size_t)b * NN * DD;
  __shared__ unsigned short stage[4 * 128 * 40];   // 40KB; also reused as float buf
  int t = threadIdx.x;
  int wave = t >> 6, lane = t & 63;
  int wr = (wave & 1) * 64, wc = (wave >> 1) * 64;
  int lrow = lane & 15, quad = lane >> 4;
  f32x4 accH[4][4] = {}, accL[4][4] = {};
  const unsigned short* src = (wave == 0) ? XH + (size_t)i0 * DD
                             : (wave == 1) ? XL + (size_t)i0 * DD
                             : (wave == 2) ? XH + (size_t)j0 * DD
                                           : XL + (size_t)j0 * DD;
  for (int k0 = 0; k0 < DD; k0 += 32) {
#pragma unroll
    for (int e = 0; e < 8; ++e) {
      int row = lane + 64 * (e & 1);
      int o = e >> 1;
      *reinterpret_cast<int4*>(&stage[(wave * 128 + row) * 40 + o * 8]) =
          *reinterpret_cast<const int4*>(&src[(size_t)row * DD + k0 + o * 8]);
    }
    __syncthreads();
    f16x8 ah[4], al[4], bh[4], bl[4];
#pragma unroll
    for (int i = 0; i < 4; ++i) {
      int ra = wr + i * 16 + lrow;
      int rb = wc + i * 16 + lrow;
      ah[i] = *reinterpret_cast<const f16x8*>(&stage[(0 * 128 + ra) * 40 + quad * 8]);
      al[i] = *reinterpret_cast<const f16x8*>(&stage[(1 * 128 + ra) * 40 + quad * 8]);
      bh[i] = *reinterpret_cast<const f16x8*>(&stage[(2 * 128 + rb) * 40 + quad * 8]);
      bl[i] = *reinterpret_cast<const f16x8*>(&stage[(3 * 128 + rb) * 40 + quad * 8]);
    }
#pragma unroll
    for (int i = 0; i < 4; ++i) {
#pragma unroll
      for (int j = 0; j < 4; ++j) {
        accH[i][j] = __builtin_amdgcn_mfma_f32_16x16x32_f16(ah[i], bh[j], accH[i][j], 0, 0, 0);
        accL[i][j] = __builtin_amdgcn_mfma_f32_16x16x32_f16(ah[i], bl[j], accL[i][j], 0, 0, 0);
        accL[i][j] = __builtin_amdgcn_mfma_f32_16x16x32_f16(al[i], bh[j], accL[i][j], 0, 0, 0);
      }
    }
    __syncthreads();
  }
#pragma unroll
  for (int i = 0; i < 4; ++i)
#pragma unroll
    for (int j = 0; j < 4; ++j)
#pragma unroll
      for (int reg = 0; reg < 4; ++reg)
        accH[i][j][reg] = fmaxf(accH[i][j][reg] + accL[i][j][reg] * 4.8828125e-4f, 0.f);
  float* buf = (float*)stage;   // [64][132] floats = 33.8 KB <= 40 KB
  int rr = t >> 4, cc = t & 15;
  for (int half = 0; half < 2; ++half) {
    __syncthreads();
    if ((wr >> 6) == half) {
#pragma unroll
      for (int i = 0; i < 4; ++i)
#pragma unroll
        for (int j = 0; j < 4; ++j)
#pragma unroll
          for (int reg = 0; reg < 4; ++reg)
            buf[(i * 16 + quad * 4 + reg) * 132 + wc + j * 16 + lrow] = accH[i][j][reg];
    }
    __syncthreads();
#pragma unroll
    for (int i = 0; i < 4; ++i) {
      int row = rr + i * 16;
#pragma unroll
      for (int q = 0; q < 2; ++q) {
        int col = cc * 4 + q * 64;
        *reinterpret_cast<float4*>(&Mb[(size_t)(i0 + half * 64 + row) * NN + j0 + col]) =
            *reinterpret_cast<float4*>(&buf[row * 132 + col]);
      }
    }
  }
  if (I != J) {
    for (int half = 0; half < 2; ++half) {
      __syncthreads();
      if ((wc >> 6) == half) {
#pragma unroll
        for (int i = 0; i < 4; ++i)
#pragma unroll
          for (int j = 0; j < 4; ++j)
#pragma unroll
            for (int reg = 0; reg < 4; ++reg)
              buf[(j * 16 + lrow) * 132 + wr + i * 16 + quad * 4 + reg] = accH[i][j][reg];
      }
      __syncthreads();
#pragma unroll
      for (int i = 0; i < 4; ++i) {
        int row = rr + i * 16;
#pragma unroll
        for (int q = 0; q < 2; ++q) {
          int col = cc * 4 + q * 64;
          *reinterpret_cast<float4*>(&Mb[(size_t)(j0 + half * 64 + row) * NN + i0 + col]) =
              *reinterpret_cast<float4*>(&buf[row * 132 + col]);
        }
      }
    }
  }
}

// ---------------------------------------------------------------------------
// K4: per-row 21st-largest via bisection, ONE WAVE PER ROW, row in VGPRs.
// R13/R14 post-mortem: a pre-loop asm fence does NOT stop the allocator from
// sinking the loads into the loop (VGPR stayed 36-40; ~2 GB of L2 re-reads).
// Fix: the opaque "+v" asm is INSIDE the loop -> every u[i] is a loop-carried
// VGPR dependency each iteration; spilling would cost a scratch round-trip per
// element per iteration, so the allocator must keep all 64 resident
// (budget via __launch_bounds__(256,2)).  Count via ballot+popc (SALU).
// ---------------------------------------------------------------------------
__global__ __launch_bounds__(256, 2) void k_topk(const float* __restrict__ M,
                                                 float* __restrict__ thr) {
  int b = blockIdx.y;
  int wave = threadIdx.x >> 6, lane = threadIdx.x & 63;
  int n = blockIdx.x * 4 + wave;
  const float* row = M + (size_t)b * NN * NN + (size_t)n * NN;
  unsigned int u[64];
#pragma unroll
  for (int e = 0; e < 16; ++e)
    *reinterpret_cast<uint4*>(&u[e * 4]) =
        *reinterpret_cast<const uint4*>(&row[lane * 4 + e * 256]);
  unsigned int lo = 0u, hi = 0x40000000u;   // values in [0, ~1.0+eps]; 2.0f bound
  while (lo < hi) {
    unsigned int mid = lo + ((hi - lo + 1) >> 1);
    int c = 0;
#pragma unroll
    for (int i = 0; i < 64; ++i) {
      asm volatile("" : "+v"(u[i]));        // loop-carried: forces VGPR residency
      c += (int)__popcll(__ballot(u[i] >= mid));
    }
    if (c >= 21) lo = mid; else hi = mid - 1;
  }
  if (lane == 0) thr[b * NN + n] = __uint_as_float(lo);
}

// ---------------------------------------------------------------------------
// K5: sparsify + symmetrize.  aff1 is bit-exact symmetric, so
// As[i][j] = a*(1(a>=thr_i) + 1(a>=thr_j)) needs ONLY the (I,J) tile.
// Writes bf16 As packed into each tile's fp32 footprint + degree sums.
// ---------------------------------------------------------------------------
__global__ __launch_bounds__(256) void k_symm(float* __restrict__ M, const float* __restrict__ thr,
                                              float* __restrict__ dsum) {
  int L = blockIdx.x;          // 0..2079 triangular (64 tiles/dim)
  int b = blockIdx.y;
  int I = 0;
  while (L >= 64 - I) { L -= 64 - I; ++I; }
  int J = I + L;
  float* Mb = M + (size_t)b * NN * NN;
  unsigned short* Mus = (unsigned short*)Mb;
  const float* th = thr + b * NN;
  __shared__ float A[64][65];
  int t = threadIdx.x;
  int i0 = I * 64, j0 = J * 64;
  float areg[16];
#pragma unroll
  for (int e = 0; e < 16; ++e) {
    int lin = t + e * 256;
    int i = lin >> 6, j = lin & 63;
    areg[e] = Mb[(size_t)(i0 + i) * NN + j0 + j];
  }
#pragma unroll
  for (int e = 0; e < 16; ++e) {
    int lin = t + e * 256;
    int i = lin >> 6, j = lin & 63;
    float a = areg[e];
    float v = a * ((a >= th[i0 + i] ? 1.f : 0.f) + (a >= th[j0 + j] ? 1.f : 0.f));
    A[i][j] = v;
  }
  __syncthreads();
  {
    int i = t >> 2, seg = (t & 3) * 16;
    float v[16];
#pragma unroll
    for (int q = 0; q < 4; ++q)
      *reinterpret_cast<float4*>(&v[q * 4]) = *reinterpret_cast<float4*>(&A[i][seg + q * 4]);
    unsigned int pk[8];
#pragma unroll
    for (int q = 0; q < 8; ++q) pk[q] = pack2(v[2 * q], v[2 * q + 1]);
    size_t ub = 2 * (size_t)(i0 + i) * NN + 2 * (size_t)j0 + seg;
    *reinterpret_cast<int4*>(&Mus[ub])     = *reinterpret_cast<int4*>(&pk[0]);
    *reinterpret_cast<int4*>(&Mus[ub + 8]) = *reinterpret_cast<int4*>(&pk[4]);
  }
  if (I != J) {   // As is symmetric: mirror footprint gets A^T
    int j = t >> 2, seg = (t & 3) * 16;
    float v[16];
#pragma unroll
    for (int e = 0; e < 16; ++e) v[e] = A[seg + e][j];
    unsigned int pk[8];
#pragma unroll
    for (int q = 0; q < 8; ++q) pk[q] = pack2(v[2 * q], v[2 * q + 1]);
    size_t ub = 2 * (size_t)(j0 + j) * NN + 2 * (size_t)i0 + seg;
    *reinterpret_cast<int4*>(&Mus[ub])     = *reinterpret_cast<int4*>(&pk[0]);
    *reinterpret_cast<int4*>(&Mus[ub + 8]) = *reinterpret_cast<int4*>(&pk[4]);
  }
  if (t < 64) {
    float s = 0.f;
#pragma unroll
    for (int j = 0; j < 64; ++j) s += A[t][j];
    atomicAdd(&dsum[b * NN + i0 + t], s);
  } else if (t < 128 && I != J) {
    int j = t - 64;
    float s = 0.f;
#pragma unroll
    for (int i = 0; i < 64; ++i) s += A[i][j];
    atomicAdd(&dsum[b * NN + j0 + j], s);
  }
}

// ---------------------------------------------------------------------------
// K6: d = (d + 1e-10)^-0.5
// ---------------------------------------------------------------------------
__global__ void k_fin_d(float* __restrict__ d) {
  int g = blockIdx.x * 256 + threadIdx.x;
  if (g < BB * NN) d[g] = 1.f / sqrtf(d[g] + 1e-10f);
}

// ---------------------------------------------------------------------------
// K7: ybh[b][c][n] = bf16(d1[b][n] * pred[b][c][n]), zero-padded to 32 classes
// ---------------------------------------------------------------------------
__global__ void k_make_yb(const float* __restrict__ pred, const float* __restrict__ d1,
                          unsigned short* __restrict__ ybh) {
  int g = blockIdx.x * 256 + threadIdx.x;   // BB*32*NN/4 threads
  int idx = g * 4;
  int b = idx / (32 * NN);
  int c = (idx / NN) & 31;
  int n = idx & (NN - 1);
  ushort4 o = make_ushort4(0, 0, 0, 0);
  if (c < CC) {
    float4 p = *reinterpret_cast<const float4*>(&pred[((size_t)b * CC + c) * NN + n]);
    const float* dd = d1 + b * NN + n;
    o.x = f2b(p.x * dd[0]); o.y = f2b(p.y * dd[1]);
    o.z = f2b(p.z * dd[2]); o.w = f2b(p.w * dd[3]);
  }
  *reinterpret_cast<ushort4*>(&ybh[idx]) = o;
}

// ---------------------------------------------------------------------------
// K8: p2 via MFMA.  GEMM: M=n (64-tile), N=c (32 padded), K=m (4096).
// ---------------------------------------------------------------------------
__global__ __launch_bounds__(256) void k_p2_mfma(
    const float* __restrict__ M, const unsigned short* __restrict__ ybh,
    const float* __restrict__ d1, float* __restrict__ p2b) {
  int b = blockIdx.y;
  int n0 = blockIdx.x * 64;
  const unsigned short* Mus = (const unsigned short*)(M + (size_t)b * NN * NN);
  const unsigned short* Y = ybh + (size_t)b * 32 * NN;
  __shared__ unsigned short As[64][72];
  __shared__ unsigned short Ys[32][72];
  int t = threadIdx.x;
  int wave = t >> 6, lane = t & 63;
  int wn = (wave & 1) * 32;
  int wc = (wave >> 1) * 16;
  int lrow = lane & 15, quad = lane >> 4;
  f32x4 acc[2] = {{0.f,0.f,0.f,0.f},{0.f,0.f,0.f,0.f}};
  int sr = t >> 3, scc = (t & 7) * 8;
  for (int m0 = 0; m0 < NN; m0 += 64) {
#pragma unroll
    for (int e = 0; e < 2; ++e) {
      int rr = sr + e * 32;
      *reinterpret_cast<int4*>(&As[rr][scc]) =
          *reinterpret_cast<const int4*>(&Mus[2 * (size_t)(n0 + rr) * NN + 2 * (size_t)m0 + scc]);
    }
    *reinterpret_cast<int4*>(&Ys[sr][scc]) =
        *reinterpret_cast<const int4*>(&Y[(size_t)sr * NN + m0 + scc]);
    __syncthreads();
#pragma unroll
    for (int kc = 0; kc < 2; ++kc) {
      int ko = kc * 32 + quad * 8;
      bf16x8 bfr = *reinterpret_cast<const bf16x8*>(&Ys[wc + lrow][ko]);
#pragma unroll
      for (int i = 0; i < 2; ++i) {
        bf16x8 af = *reinterpret_cast<const bf16x8*>(&As[wn + i * 16 + lrow][ko]);
        acc[i] = __builtin_amdgcn_mfma_f32_16x16x32_bf16(af, bfr, acc[i], 0, 0, 0);
      }
    }
    __syncthreads();
  }
  int c = wc + lrow;
  if (c < CC) {
#pragma unroll
    for (int i = 0; i < 2; ++i) {
#pragma unroll
      for (int reg = 0; reg < 4; ++reg) {
        int n = n0 + wn + i * 16 + quad * 4 + reg;
        p2b[((size_t)b * NN + n) * CC + c] = d1[b * NN + n] * acc[i][reg];
      }
    }
  }
}

// ---------------------------------------------------------------------------
// K9: fused blend + 19x19 conv x2 -> pred_out, then softmax + cosine-normalize
// ---------------------------------------------------------------------------
__global__ __launch_bounds__(256) void k_pred_head(const float* __restrict__ pred,
    const float* __restrict__ p2b, const float* __restrict__ maskb,
    const float* __restrict__ w1, const float* __restrict__ b1,
    const float* __restrict__ w2, const float* __restrict__ b2,
    float* __restrict__ out, float* __restrict__ spnT) {
  __shared__ float sw1[CC * CC], sw2[CC * CC], sb1[CC], sb2[CC];
  int t = threadIdx.x;
  for (int i = t; i < CC * CC; i += 256) { sw1[i] = w1[i]; sw2[i] = w2[i]; }
  if (t < CC) { sb1[t] = b1[t]; sb2[t] = b2[t]; }
  __syncthreads();
  int g = blockIdx.x * 256 + t;
  int b = g >> 12, n = g & (NN - 1);
  float m = maskb[g];
  float ca = (m > 0.5f) ? 0.2f : 0.8f;
  float cb = (m > 0.5f) ? 0.8f : 0.2f;
  const float* P = pred + (size_t)b * CC * NN + n;
  const float* Q = p2b + (size_t)g * CC;
  float p3[CC];
#pragma unroll
  for (int c = 0; c < CC; ++c) p3[c] = ca * Q[c] + cb * P[(size_t)c * NN];
  float midv[CC];
#pragma unroll
  for (int o = 0; o < CC; ++o) {
    float s = sb1[o];
#pragma unroll
    for (int c = 0; c < CC; ++c) s += sw1[o * CC + c] * p3[c];
    midv[o] = s;
  }
  float ov[CC];
  float mx = -1e30f;
#pragma unroll
  for (int o = 0; o < CC; ++o) {
    float s = sb2[o];
#pragma unroll
    for (int c = 0; c < CC; ++c) s += sw2[o * CC + c] * midv[c];
    ov[o] = s;
    out[(size_t)b * CC * NN + (size_t)o * NN + n] = s;
    mx = fmaxf(mx, s);
  }
  float se = 0.f;
  float e[CC];
#pragma unroll
  for (int o = 0; o < CC; ++o) { e[o] = expf(ov[o] - mx); se += e[o]; }
  float inv = 1.f / se;
  float nrm = 0.f;
#pragma unroll
  for (int o = 0; o < CC; ++o) { float sp = e[o] * inv; e[o] = sp; nrm += sp * sp; }
  float rn = 1.f / (sqrtf(nrm) + 1e-9f);
#pragma unroll
  for (int o = 0; o < CC; ++o) spnT[(size_t)b * CC * NN + (size_t)o * NN + n] = e[o] * rn;
}

// ---------------------------------------------------------------------------
// K10: aff_f = bitmask ? clamp(Gram(spn),0) : 0   (K=19), writes bf16.
// ---------------------------------------------------------------------------
__global__ __launch_bounds__(256) void k_gram2(const float* __restrict__ spnT,
    const unsigned int* __restrict__ bits, unsigned short* __restrict__ Mh) {
  int L = blockIdx.x;          // 0..2079 triangular (64 tiles/dim)
  int b = blockIdx.y;
  int I = 0;
  while (L >= 64 - I) { L -= 64 - I; ++I; }
  int J = I + L;
  const float* X = spnT + (size_t)b * CC * NN;
  unsigned short* Mb = Mh + (size_t)b * NN * NN;
  __shared__ float sA[CC][64], sB[CC][64];
  __shared__ unsigned int bI[64], bJ[64];
  __shared__ float tr[64][65];
  int t = threadIdx.x;
  int r = t >> 4, c = t & 15;
  int i0 = I * 64, j0 = J * 64;
  for (int e = t; e < CC * 64; e += 256) {
    int k = e >> 6, col = e & 63;
    sA[k][col] = X[(size_t)k * NN + i0 + col];
    sB[k][col] = X[(size_t)k * NN + j0 + col];
  }
  if (t < 64) bI[t] = bits[b * NN + i0 + t];
  else if (t < 128) bJ[t - 64] = bits[b * NN + j0 + t - 64];
  __syncthreads();
  float acc[4][4] = {};
#pragma unroll
  for (int k = 0; k < CC; ++k) {
    float av[4], bv[4];
#pragma unroll
    for (int i = 0; i < 4; ++i) av[i] = sA[k][r * 4 + i];
#pragma unroll
    for (int j = 0; j < 4; ++j) bv[j] = sB[k][c * 4 + j];
#pragma unroll
    for (int i = 0; i < 4; ++i) {
#pragma unroll
      for (int j = 0; j < 4; ++j) acc[i][j] += av[i] * bv[j];
    }
  }
#pragma unroll
  for (int i = 0; i < 4; ++i) {
#pragma unroll
    for (int j = 0; j < 4; ++j) {
      bool keep = (bI[r * 4 + i] & bJ[c * 4 + j]) != 0u;
      acc[i][j] = keep ? fmaxf(acc[i][j], 0.f) : 0.f;
    }
    ushort4 v;
    v.x = f2b(acc[i][0]); v.y = f2b(acc[i][1]); v.z = f2b(acc[i][2]); v.w = f2b(acc[i][3]);
    *reinterpret_cast<ushort4*>(&Mb[(size_t)(i0 + r * 4 + i) * NN + j0 + c * 4]) = v;
  }
  if (I != J) {
#pragma unroll
    for (int i = 0; i < 4; ++i) {
#pragma unroll
      for (int j = 0; j < 4; ++j) tr[r * 4 + i][c * 4 + j] = acc[i][j];
    }
    __syncthreads();
#pragma unroll
    for (int e = 0; e < 16; ++e) {
      int lin = t + e * 256;
      int jr = lin >> 6, ic = lin & 63;
      Mb[(size_t)(j0 + jr) * NN + i0 + ic] = f2b(tr[ic][jr]);
    }
  }
}

// ---------------------------------------------------------------------------
// K11: d2[n] = (row_sum(aff_f bf16) + 1e-10)^-0.5
// ---------------------------------------------------------------------------
__global__ __launch_bounds__(256) void k_rowsum2h(const unsigned short* __restrict__ Mh,
                                                  float* __restrict__ d2) {
  int b = blockIdx.y, n = blockIdx.x;
  const unsigned short* row = Mh + (size_t)b * NN * NN + (size_t)n * NN;
  int t = threadIdx.x;
  float s = 0.f;
#pragma unroll
  for (int i = 0; i < 8; ++i) {
    unsigned int u = *reinterpret_cast<const unsigned int*>(&row[(i * 256 + t) * 2]);
    s += __uint_as_float(u << 16) + __uint_as_float(u & 0xffff0000u);
  }
  for (int off = 32; off > 0; off >>= 1) s += __shfl_down(s, off);
  __shared__ float p4[4];
  int wid = t >> 6, lane = t & 63;
  if (lane == 0) p4[wid] = s;
  __syncthreads();
  if (t == 0) d2[b * NN + n] = 1.f / sqrtf(p4[0] + p4[1] + p4[2] + p4[3] + 1e-10f);
}

// ---------------------------------------------------------------------------
// K12a: zb[b][d][m] = bf16(feat[b][d][m] * d2[b][m])
// ---------------------------------------------------------------------------
__global__ void k_make_z(const float* __restrict__ feat, const float* __restrict__ d2,
                         unsigned short* __restrict__ zb) {
  int g = blockIdx.x * 256 + threadIdx.x;   // BB*DD*NN/4 threads
  int idx = g * 4;
  int b = idx / (DD * NN);
  int m = idx & (NN - 1);
  float4 f = *reinterpret_cast<const float4*>(&feat[idx]);
  const float* dd = d2 + b * NN + m;
  ushort4 o;
  o.x = f2b(f.x * dd[0]); o.y = f2b(f.y * dd[1]);
  o.z = f2b(f.z * dd[2]); o.w = f2b(f.w * dd[3]);
  *reinterpret_cast<ushort4*>(&zb[idx]) = o;
}

// K12b: convert projection weights to bf16
__global__ void k_prep_w(const float* __restrict__ w1, const float* __restrict__ w2,
                         unsigned short* __restrict__ wb1, unsigned short* __restrict__ wb2) {
  int g = blockIdx.x * 256 + threadIdx.x;   // DD*DD threads
  wb1[g] = f2b(w1[g]);
  wb2[g] = f2b(w2[g]);
}

// ---------------------------------------------------------------------------
// K13: new_feat via MFMA with split-K x4.  GEMM: M=d(64), N=n(64), K=1024.
// ---------------------------------------------------------------------------
__global__ __launch_bounds__(256) void k_newfeat_mfma(
    const unsigned short* __restrict__ Mh, const unsigned short* __restrict__ zb,
    float* __restrict__ nfp) {
  int zz = blockIdx.z;                 // b*KSPLIT + ks
  int b = zz / KSPLIT, ks = zz % KSPLIT;
  int nblk = blockIdx.x;   // 64
  int dblk = blockIdx.y;   // 4
  const int KLEN = NN / KSPLIT;        // 1024
  const unsigned short* A = zb + (size_t)b * DD * NN + (size_t)(dblk * 64) * NN + ks * KLEN;
  const unsigned short* Bm = Mh + (size_t)b * NN * NN + (size_t)(nblk * 64) * NN + ks * KLEN;
  __shared__ unsigned short As[64][72];
  __shared__ unsigned short Bs[64][72];
  int t = threadIdx.x;
  int wave = t >> 6, lane = t & 63;
  int wd = (wave & 1) * 32, wn = (wave >> 1) * 32;
  int lrow = lane & 15, quad = lane >> 4;
  f32x4 acc[2][2] = {{{0.f,0.f,0.f,0.f},{0.f,0.f,0.f,0.f}},{{0.f,0.f,0.f,0.f},{0.f,0.f,0.f,0.f}}};
  int sr = t >> 3, sc = (t & 7) * 8;
  for (int m0 = 0; m0 < KLEN; m0 += 64) {
#pragma unroll
    for (int e = 0; e < 2; ++e) {
      int rr = sr + e * 32;
      *reinterpret_cast<int4*>(&As[rr][sc]) =
          *reinterpret_cast<const int4*>(&A[(size_t)rr * NN + m0 + sc]);
      *reinterpret_cast<int4*>(&Bs[rr][sc]) =
          *reinterpret_cast<const int4*>(&Bm[(size_t)rr * NN + m0 + sc]);
    }
    __syncthreads();
#pragma unroll
    for (int kc = 0; kc < 2; ++kc) {
      int ko = kc * 32 + quad * 8;
      bf16x8 af[2], bfr[2];
#pragma unroll
      for (int i = 0; i < 2; ++i) {
        af[i]  = *reinterpret_cast<const bf16x8*>(&As[wd + i * 16 + lrow][ko]);
        bfr[i] = *reinterpret_cast<const bf16x8*>(&Bs[wn + i * 16 + lrow][ko]);
      }
#pragma unroll
      for (int i = 0; i < 2; ++i)
#pragma unroll
        for (int j = 0; j < 2; ++j)
          acc[i][j] = __builtin_amdgcn_mfma_f32_16x16x32_bf16(af[i], bfr[j], acc[i][j], 0, 0, 0);
    }
    __syncthreads();
  }
#pragma unroll
  for (int j = 0; j < 2; ++j) {
    int n = nblk * 64 + wn + j * 16 + lrow;
#pragma unroll
    for (int i = 0; i < 2; ++i) {
      int d = dblk * 64 + wd + i * 16 + quad * 4;
      float4 v = make_float4(acc[i][j].x, acc[i][j].y, acc[i][j].z, acc[i][j].w);
      *reinterpret_cast<float4*>(&nfp[((size_t)zz * NN + n) * DD + d]) = v;
    }
  }
}

// ---------------------------------------------------------------------------
// K13b: reduce split-K partials, scale by d2, emit bf16 nfh[b][n][d]
// ---------------------------------------------------------------------------
__global__ void k_nf_reduce(const float* __restrict__ nfp, const float* __restrict__ d2,
                            unsigned short* __restrict__ nfh) {
  int g = blockIdx.x * 256 + threadIdx.x;   // BB*NN*DD/4 threads
  int idx = g * 4;
  int b = idx / (NN * DD);
  int n = (idx / DD) & (NN - 1);
  size_t base = (size_t)idx + (size_t)b * (KSPLIT - 1) * NN * DD;
  float4 s = make_float4(0.f, 0.f, 0.f, 0.f);
#pragma unroll
  for (int ks = 0; ks < KSPLIT; ++ks) {
    float4 v = *reinterpret_cast<const float4*>(&nfp[base + (size_t)ks * NN * DD]);
    s.x += v.x; s.y += v.y; s.z += v.z; s.w += v.w;
  }
  float sc = d2[b * NN + n];
  ushort4 o;
  o.x = f2b(s.x * sc); o.y = f2b(s.y * sc); o.z = f2b(s.z * sc); o.w = f2b(s.w * sc);
  *reinterpret_cast<ushort4*>(&nfh[idx]) = o;
}

// ---------------------------------------------------------------------------
// K14: conv1 via MFMA. GEMM: M=n, N=o1, K=d.
// ---------------------------------------------------------------------------
__global__ __launch_bounds__(256) void k_conv1_mfma(
    const unsigned short* __restrict__ nfh, const unsigned short* __restrict__ wb1,
    const float* __restrict__ b1, unsigned short* __restrict__ midh) {
  int b = blockIdx.z;
  int nblk = blockIdx.x;   // 64
  int oblk = blockIdx.y;   // 4
  int n0 = nblk * 64, o0 = oblk * 64;
  __shared__ unsigned short As[64][72];
  __shared__ unsigned short Bs[64][72];
  int t = threadIdx.x;
  int wave = t >> 6, lane = t & 63;
  int wn = (wave & 1) * 32, wo = (wave >> 1) * 32;
  int lrow = lane & 15, quad = lane >> 4;
  f32x4 acc[2][2] = {{{0.f,0.f,0.f,0.f},{0.f,0.f,0.f,0.f}},{{0.f,0.f,0.f,0.f},{0.f,0.f,0.f,0.f}}};
  int sr = t >> 3, sc = (t & 7) * 8;
  for (int d0 = 0; d0 < DD; d0 += 64) {
#pragma unroll
    for (int e = 0; e < 2; ++e) {
      int rr = sr + e * 32;
      *reinterpret_cast<int4*>(&As[rr][sc]) =
          *reinterpret_cast<const int4*>(&nfh[((size_t)b * NN + n0 + rr) * DD + d0 + sc]);
      *reinterpret_cast<int4*>(&Bs[rr][sc]) =
          *reinterpret_cast<const int4*>(&wb1[(size_t)(o0 + rr) * DD + d0 + sc]);
    }
    __syncthreads();
#pragma unroll
    for (int kc = 0; kc < 2; ++kc) {
      int ko = kc * 32 + quad * 8;
      bf16x8 af[2], bfr[2];
#pragma unroll
      for (int i = 0; i < 2; ++i) {
        af[i]  = *reinterpret_cast<const bf16x8*>(&As[wn + i * 16 + lrow][ko]);
        bfr[i] = *reinterpret_cast<const bf16x8*>(&Bs[wo + i * 16 + lrow][ko]);
      }
#pragma unroll
      for (int i = 0; i < 2; ++i)
#pragma unroll
        for (int j = 0; j < 2; ++j)
          acc[i][j] = __builtin_amdgcn_mfma_f32_16x16x32_bf16(af[i], bfr[j], acc[i][j], 0, 0, 0);
    }
    __syncthreads();
  }
#pragma unroll
  for (int j = 0; j < 2; ++j) {
    int o = o0 + wo + j * 16 + lrow;
    float bias = b1[o];
#pragma unroll
    for (int i = 0; i < 2; ++i) {
      int nb = n0 + wn + i * 16 + quad * 4;
      ushort4 v;
      v.x = f2b(fmaxf(acc[i][j].x + bias, 0.f));
      v.y = f2b(fmaxf(acc[i][j].y + bias, 0.f));
      v.z = f2b(fmaxf(acc[i][j].z + bias, 0.f));
      v.w = f2b(fmaxf(acc[i][j].w + bias, 0.f));
      *reinterpret_cast<ushort4*>(&midh[((size_t)b * DD + o) * NN + nb]) = v;
    }
  }
}

// ---------------------------------------------------------------------------
// K15: conv2 via MFMA. GEMM: M=n, N=o2, K=o1.
// ---------------------------------------------------------------------------
__global__ __launch_bounds__(256) void k_conv2_mfma(
    const unsigned short* __restrict__ midh, const unsigned short* __restrict__ wb2,
    const float* __restrict__ b2, float* __restrict__ outp) {
  int b = blockIdx.z;
  int nblk = blockIdx.x;   // 64
  int oblk = blockIdx.y;   // 4
  int n0 = nblk * 64, o0 = oblk * 64;
  __shared__ unsigned short As[64][72];
  __shared__ unsigned short Bs[64][72];
  int t = threadIdx.x;
  int wave = t >> 6, lane = t & 63;
  int wn = (wave & 1) * 32, wo = (wave >> 1) * 32;
  int lrow = lane & 15, quad = lane >> 4;
  f32x4 acc[2][2] = {{{0.f,0.f,0.f,0.f},{0.f,0.f,0.f,0.f}},{{0.f,0.f,0.f,0.f},{0.f,0.f,0.f,0.f}}};
  int sr = t >> 3, sc = (t & 7) * 8;
  for (int d0 = 0; d0 < DD; d0 += 64) {
#pragma unroll
    for (int e = 0; e < 2; ++e) {
      int rr = sr + e * 32;
      *reinterpret_cast<int4*>(&Bs[rr][sc]) =
          *reinterpret_cast<const int4*>(&wb2[(size_t)(o0 + rr) * DD + d0 + sc]);
      unsigned short v[8];
      *reinterpret_cast<int4*>(v) =
          *reinterpret_cast<const int4*>(&midh[((size_t)b * DD + d0 + rr) * NN + n0 + sc]);
#pragma unroll
      for (int j = 0; j < 8; ++j) As[sc + j][rr] = v[j];
    }
    __syncthreads();
#pragma unroll
    for (int kc = 0; kc < 2; ++kc) {
      int ko = kc * 32 + quad * 8;
      bf16x8 af[2], bfr[2];
#pragma unroll
      for (int i = 0; i < 2; ++i) {
        af[i]  = *reinterpret_cast<const bf16x8*>(&As[wn + i * 16 + lrow][ko]);
        bfr[i] = *reinterpret_cast<const bf16x8*>(&Bs[wo + i * 16 + lrow][ko]);
      }
#pragma unroll
      for (int i = 0; i < 2; ++i)
#pragma unroll
        for (int j = 0; j < 2; ++j)
          acc[i][j] = __builtin_amdgcn_mfma_f32_16x16x32_bf16(af[i], bfr[j], acc[i][j], 0, 0, 0);
    }
    __syncthreads();
  }
#pragma unroll
  for (int j = 0; j < 2; ++j) {
    int o = o0 + wo + j * 16 + lrow;
    float bias = b2[o];
#pragma unroll
    for (int i = 0; i < 2; ++i) {
      int nb = n0 + wn + i * 16 + quad * 4;
      float4 v = make_float4(acc[i][j].x + bias, acc[i][j].y + bias,
                             acc[i][j].z + bias, acc[i][j].w + bias);
      *reinterpret_cast<float4*>(&outp[((size_t)b * DD + o) * NN + nb]) = v;
    }
  }
}

// ---------------------------------------------------------------------------
extern "C" void kernel_launch(void* const* d_in, const int* in_sizes, int n_in,
                              void* d_out, int out_size, void* d_ws, size_t ws_size,
                              hipStream_t stream) {
  (void)in_sizes; (void)n_in; (void)out_size; (void)ws_size;
  const float* pred   = (const float*)d_in[0];
  const float* feat   = (const float*)d_in[1];
  const float* w_cls1 = (const float*)d_in[2];
  const float* b_cls1 = (const float*)d_in[3];
  const float* w_cls2 = (const float*)d_in[4];
  const float* b_cls2 = (const float*)d_in[5];
  const float* w_pro1 = (const float*)d_in[6];
  const float* b_pro1 = (const float*)d_in[7];
  const float* w_pro2 = (const float*)d_in[8];
  const float* b_pro2 = (const float*)d_in[9];
  const float* cw     = (const float*)d_in[10];
  float* out = (float*)d_out;

  // workspace layout
  float* Mbuf = (float*)d_ws;                               // B*N*N fp32 (aff1 / packed-bf16 As / bf16 aff_f)
  float* spnT = Mbuf + (size_t)BB * NN * NN;
  float* p2b  = spnT + (size_t)BB * CC * NN;
  float* thr  = p2b + (size_t)BB * NN * CC;
  float* dsum = thr + BB * NN;
  float* d2s  = dsum + BB * NN;
  float* maskb = d2s + BB * NN;
  unsigned int* ohbits = (unsigned int*)(maskb + BB * NN);
  unsigned short* xh   = (unsigned short*)(ohbits + BB * NN);  // B*N*D fp16 hi
  unsigned short* xl   = xh + (size_t)BB * NN * DD;            // B*N*D fp16 lo*2^11
  unsigned short* nfh  = xl + (size_t)BB * NN * DD;            // B*N*D bf16
  unsigned short* midh = nfh + (size_t)BB * NN * DD;           // B*D*N bf16
  unsigned short* zb   = midh + (size_t)BB * DD * NN;          // B*D*N bf16
  unsigned short* wb1  = zb + (size_t)BB * DD * NN;            // D*D bf16
  unsigned short* wb2  = wb1 + (size_t)DD * DD;                // D*D bf16
  unsigned short* ybh  = wb2 + (size_t)DD * DD;                // B*32*N bf16 (padded y)
  unsigned short* Mh   = (unsigned short*)Mbuf;
  // split-K partials alias the upper half of Mbuf (dead after k_p2)
  float* nfp = (float*)(Mh + (size_t)BB * NN * NN);            // KSPLIT*B*N*D fp32 = 32 MB

  hipMemsetAsync(dsum, 0, sizeof(float) * BB * NN, stream);
  hipMemsetAsync(ohbits, 0, sizeof(unsigned int) * BB * NN, stream);

  // --- pred branch ---
  k_mask_bits<<<BB * NN / 256, 256, 0, stream>>>(pred, cw, maskb, ohbits);
  k_norm_feat<<<BB * NN / 64, 64, 0, stream>>>(feat, xh, xl);
  k_gram1<<<dim3(528, BB), 256, 0, stream>>>(xh, xl, Mbuf);
  k_topk<<<dim3(NN / 4, BB), 256, 0, stream>>>(Mbuf, thr);
  k_symm<<<dim3(2080, BB), 256, 0, stream>>>(Mbuf, thr, dsum);
  k_fin_d<<<BB * NN / 256, 256, 0, stream>>>(dsum);
  k_make_yb<<<BB * 32 * NN / 4 / 256, 256, 0, stream>>>(pred, dsum, ybh);
  k_p2_mfma<<<dim3(NN / 64, BB), 256, 0, stream>>>(Mbuf, ybh, dsum, p2b);
  k_pred_head<<<BB * NN / 256, 256, 0, stream>>>(pred, p2b, maskb, w_cls1, b_cls1,
                                                 w_cls2, b_cls2, out, spnT);
  // --- feat branch (bf16 MFMA) ---
  k_gram2<<<dim3(2080, BB), 256, 0, stream>>>(spnT, ohbits, Mh);
  k_rowsum2h<<<dim3(NN, BB), 256, 0, stream>>>(Mh, d2s);
  k_make_z<<<BB * DD * NN / 4 / 256, 256, 0, stream>>>(feat, d2s, zb);
  k_prep_w<<<DD * DD / 256, 256, 0, stream>>>(w_pro1, w_pro2, wb1, wb2);
  k_newfeat_mfma<<<dim3(64, 4, BB * KSPLIT), 256, 0, stream>>>(Mh, zb, nfp);
  k_nf_reduce<<<BB * NN * DD / 4 / 256, 256, 0, stream>>>(nfp, d2s, nfh);
  k_conv1_mfma<<<dim3(64, 4, BB), 256, 0, stream>>>(nfh, wb1, b_pro1, midh);
  k_conv2_mfma<<<dim3(64, 4, BB), 256, 0, stream>>>(midh, wb2, b_pro2,
                                                    out + (size_t)BB * CC * NN);
}

// Round 16
// 441.378 us; speedup vs baseline: 1.0115x; 1.0038x over previous
//
#include <hip/hip_runtime.h>

#define NN 4096   // H*W
#define DD 256    // feature channels
#define CC 19     // classes
#define BB 2      // batch
#define KSPLIT 4  // split-K factor for new_feat GEMM

typedef __attribute__((ext_vector_type(8))) short bf16x8;     // bf16 MFMA A/B frag
typedef _Float16 f16x8 __attribute__((ext_vector_type(8)));   // fp16 MFMA A/B frag
typedef __attribute__((ext_vector_type(4))) float f32x4;      // MFMA C/D frag

__device__ inline unsigned short f2b(float f) {   // fp32 -> bf16 RNE
  unsigned int u = __float_as_uint(f);
  return (unsigned short)((u + 0x7FFFu + ((u >> 16) & 1u)) >> 16);
}
__device__ inline float b2f(unsigned short h) {
  return __uint_as_float(((unsigned int)h) << 16);
}
__device__ inline unsigned int pack2(float a, float b) {
  return (unsigned int)f2b(a) | ((unsigned int)f2b(b) << 16);
}
// fp32 -> (fp16 hi, fp16 lo*2^11): hi+2^-11*lo carries ~22 mantissa bits
__device__ inline void split16(float x, unsigned short& h, unsigned short& l) {
  _Float16 hh = (_Float16)x;
  float hf = (float)hh;
  _Float16 ll = (_Float16)((x - hf) * 2048.0f);
  h = *reinterpret_cast<unsigned short*>(&hh);
  l = *reinterpret_cast<unsigned short*>(&ll);
}

// ---------------------------------------------------------------------------
// K1: softmax confidence mask + scrambled one-hot bitmasks
// ---------------------------------------------------------------------------
__global__ void k_mask_bits(const float* __restrict__ pred, const float* __restrict__ cw,
                            float* __restrict__ maskb, unsigned int* __restrict__ ohbits) {
  int g = blockIdx.x * 256 + threadIdx.x;
  if (g >= BB * NN) return;
  int b = g >> 12, n = g & (NN - 1);
  const float* p = pred + (size_t)b * CC * NN + n;
  float v[CC];
  float mx = -1e30f; int am = 0;
#pragma unroll
  for (int c = 0; c < CC; ++c) {
    float t = p[(size_t)c * NN];
    v[c] = t;
    if (t > mx) { mx = t; am = c; }
  }
  float s = 0.f;
#pragma unroll
  for (int c = 0; c < CC; ++c) s += expf(v[c] - mx);
  float pprob = 1.f / s;
  float cmax = 0.f;
#pragma unroll
  for (int c = 0; c < CC; ++c) cmax = fmaxf(cmax, cw[c]);
  float cwm = cw[am] / (cmax + 1e-10f) * 0.95f;
  maskb[g] = (pprob >= 0.95f || pprob >= cwm) ? 1.f : 0.f;
  int h = n >> 6, w = n & 63;
  int L = w * (CC * 64) + am * 64 + h;     // flat index in [W,C,H]
  atomicOr(&ohbits[b * NN + L / CC], 1u << (L % CC));
}

// ---------------------------------------------------------------------------
// K2: row-normalize features -> split fp16 hi/lo, stored [b][n][d] (d-major)
// ---------------------------------------------------------------------------
__global__ void k_norm_feat(const float* __restrict__ feat,
                            unsigned short* __restrict__ xh, unsigned short* __restrict__ xl) {
  int g = blockIdx.x * 64 + threadIdx.x;
  int b = g >> 12, n = g & (NN - 1);
  const float* f = feat + (size_t)b * DD * NN + n;
  float s = 0.f;
  for (int d = 0; d < DD; ++d) { float t = f[(size_t)d * NN]; s += t * t; }
  float r = 1.f / (sqrtf(s) + 1e-9f);
  size_t ob = ((size_t)b * NN + n) * DD;
  for (int d = 0; d < DD; d += 4) {
    ushort4 oh, ol;
    split16(f[(size_t)d * NN] * r, oh.x, ol.x);
    split16(f[(size_t)(d + 1) * NN] * r, oh.y, ol.y);
    split16(f[(size_t)(d + 2) * NN] * r, oh.z, ol.z);
    split16(f[(size_t)(d + 3) * NN] * r, oh.w, ol.w);
    *reinterpret_cast<ushort4*>(&xh[ob + d]) = oh;
    *reinterpret_cast<ushort4*>(&xl[ob + d]) = ol;
  }
}

// ---------------------------------------------------------------------------
// K3: aff1 = clamp(Gram(xn), 0) via 3-pass split-fp16 MFMA (~fp32 accuracy).
// fp32 output; LDS-staged epilogue with full-128B-line stores (R11: 132 MB).
// ---------------------------------------------------------------------------
__global__ __launch_bounds__(256, 2) void k_gram1(const unsigned short* __restrict__ xh,
                                                  const unsigned short* __restrict__ xl,
                                                  float* __restrict__ M) {
  int L = blockIdx.x;          // 0..527 triangular (32 tiles/dim)
  int b = blockIdx.y;
  int I = 0;
  while (L >= 32 - I) { L -= 32 - I; ++I; }
  int J = I + L;
  int i0 = I * 128, j0 = J * 128;
  float* Mb = M + (size_t)b * NN * NN;
  const unsigned short* XH = xh + (size_t)b * NN * DD;
  const unsigned short* XL = xl + (size_t)b * NN * DD;
  __shared__ unsigned short stage[4 * 128 * 40];   // 40KB; also reused as float buf
  int t = threadIdx.x;
  int wave = t >> 6, lane = t & 63;
  int wr = (wave & 1) * 64, wc = (wave >> 1) * 64;
  int lrow = lane & 15, quad = lane >> 4;
  f32x4 accH[4][4] = {}, accL[4][4] = {};
  const unsigned short* src = (wave == 0) ? XH + (size_t)i0 * DD
                             : (wave == 1) ? XL + (size_t)i0 * DD
                             : (wave == 2) ? XH + (size_t)j0 * DD
                                           : XL + (size_t)j0 * DD;
  for (int k0 = 0; k0 < DD; k0 += 32) {
#pragma unroll
    for (int e = 0; e < 8; ++e) {
      int row = lane + 64 * (e & 1);
      int o = e >> 1;
      *reinterpret_cast<int4*>(&stage[(wave * 128 + row) * 40 + o * 8]) =
          *reinterpret_cast<const int4*>(&src[(size_t)row * DD + k0 + o * 8]);
    }
    __syncthreads();
    f16x8 ah[4], al[4], bh[4], bl[4];
#pragma unroll
    for (int i = 0; i < 4; ++i) {
      int ra = wr + i * 16 + lrow;
      int rb = wc + i * 16 + lrow;
      ah[i] = *reinterpret_cast<const f16x8*>(&stage[(0 * 128 + ra) * 40 + quad * 8]);
      al[i] = *reinterpret_cast<const f16x8*>(&stage[(1 * 128 + ra) * 40 + quad * 8]);
      bh[i] = *reinterpret_cast<const f16x8*>(&stage[(2 * 128 + rb) * 40 + quad * 8]);
      bl[i] = *reinterpret_cast<const f16x8*>(&stage[(3 * 128 + rb) * 40 + quad * 8]);
    }
#pragma unroll
    for (int i = 0; i < 4; ++i) {
#pragma unroll
      for (int j = 0; j < 4; ++j) {
        accH[i][j] = __builtin_amdgcn_mfma_f32_16x16x32_f16(ah[i], bh[j], accH[i][j], 0, 0, 0);
        accL[i][j] = __builtin_amdgcn_mfma_f32_16x16x32_f16(ah[i], bl[j], accL[i][j], 0, 0, 0);
        accL[i][j] = __builtin_amdgcn_mfma_f32_16x16x32_f16(al[i], bh[j], accL[i][j], 0, 0, 0);
      }
    }
    __syncthreads();
  }
#pragma unroll
  for (int i = 0; i < 4; ++i)
#pragma unroll
    for (int j = 0; j < 4; ++j)
#pragma unroll
      for (int reg = 0; reg < 4; ++reg)
        accH[i][j][reg] = fmaxf(accH[i][j][reg] + accL[i][j][reg] * 4.8828125e-4f, 0.f);
  float* buf = (float*)stage;   // [64][132] floats = 33.8 KB <= 40 KB
  int rr = t >> 4, cc = t & 15;
  for (int half = 0; half < 2; ++half) {
    __syncthreads();
    if ((wr >> 6) == half) {
#pragma unroll
      for (int i = 0; i < 4; ++i)
#pragma unroll
        for (int j = 0; j < 4; ++j)
#pragma unroll
          for (int reg = 0; reg < 4; ++reg)
            buf[(i * 16 + quad * 4 + reg) * 132 + wc + j * 16 + lrow] = accH[i][j][reg];
    }
    __syncthreads();
#pragma unroll
    for (int i = 0; i < 4; ++i) {
      int row = rr + i * 16;
#pragma unroll
      for (int q = 0; q < 2; ++q) {
        int col = cc * 4 + q * 64;
        *reinterpret_cast<float4*>(&Mb[(size_t)(i0 + half * 64 + row) * NN + j0 + col]) =
            *reinterpret_cast<float4*>(&buf[row * 132 + col]);
      }
    }
  }
  if (I != J) {
    for (int half = 0; half < 2; ++half) {
      __syncthreads();
      if ((wc >> 6) == half) {
#pragma unroll
        for (int i = 0; i < 4; ++i)
#pragma unroll
          for (int j = 0; j < 4; ++j)
#pragma unroll
            for (int reg = 0; reg < 4; ++reg)
              buf[(j * 16 + lrow) * 132 + wr + i * 16 + quad * 4 + reg] = accH[i][j][reg];
      }
      __syncthreads();
#pragma unroll
      for (int i = 0; i < 4; ++i) {
        int row = rr + i * 16;
#pragma unroll
        for (int q = 0; q < 2; ++q) {
          int col = cc * 4 + q * 64;
          *reinterpret_cast<float4*>(&Mb[(size_t)(j0 + half * 64 + row) * NN + i0 + col]) =
              *reinterpret_cast<float4*>(&buf[row * 132 + col]);
        }
      }
    }
  }
}

// ---------------------------------------------------------------------------
// K4: per-row 21st-largest via bisection, ONE WAVE PER ROW, row in VGPRs.
// R13-R15 post-mortem: value-level asm fences never stopped the compiler from
// sinking the PLAIN loads into the loop (2 GB of L2 re-reads = the 76-78 us
// L2-BW floor).  Fix: issue the loads themselves as asm volatile
// global_load_dwordx4 -- a volatile asm op cannot be re-executed or
// rematerialized, so the 64 values MUST stay live in VGPRs across the loop
// (256-VGPR budget via __launch_bounds__(256,2); no spill pressure).
// ---------------------------------------------------------------------------
__global__ __launch_bounds__(256, 2) void k_topk(const float* __restrict__ M,
                                                 float* __restrict__ thr) {
  int b = blockIdx.y;
  int wave = threadIdx.x >> 6, lane = threadIdx.x & 63;
  int n = blockIdx.x * 4 + wave;
  const float* row = M + (size_t)b * NN * NN + (size_t)n * NN;
  uint4 v[16];
#pragma unroll
  for (int e = 0; e < 16; ++e) {
    unsigned long long addr = (unsigned long long)(row + lane * 4 + e * 256);
    asm volatile("global_load_dwordx4 %0, %1, off" : "=v"(v[e]) : "v"(addr));
  }
  asm volatile("s_waitcnt vmcnt(0)" ::: "memory");
  unsigned int lo = 0u, hi = 0x40000000u;   // values in [0, ~1.0+eps]; 2.0f bound
  while (lo < hi) {
    unsigned int mid = lo + ((hi - lo + 1) >> 1);
    int c = 0;
#pragma unroll
    for (int e = 0; e < 16; ++e) {
      c += (int)__popcll(__ballot(v[e].x >= mid));
      c += (int)__popcll(__ballot(v[e].y >= mid));
      c += (int)__popcll(__ballot(v[e].z >= mid));
      c += (int)__popcll(__ballot(v[e].w >= mid));
    }
    if (c >= 21) lo = mid; else hi = mid - 1;
  }
  if (lane == 0) thr[b * NN + n] = __uint_as_float(lo);
}

// ---------------------------------------------------------------------------
// K5: sparsify + symmetrize.  aff1 is bit-exact symmetric, so
// As[i][j] = a*(1(a>=thr_i) + 1(a>=thr_j)) needs ONLY the (I,J) tile.
// Writes bf16 As packed into each tile's fp32 footprint + degree sums.
// ---------------------------------------------------------------------------
__global__ __launch_bounds__(256) void k_symm(float* __restrict__ M, const float* __restrict__ thr,
                                              float* __restrict__ dsum) {
  int L = blockIdx.x;          // 0..2079 triangular (64 tiles/dim)
  int b = blockIdx.y;
  int I = 0;
  while (L >= 64 - I) { L -= 64 - I; ++I; }
  int J = I + L;
  float* Mb = M + (size_t)b * NN * NN;
  unsigned short* Mus = (unsigned short*)Mb;
  const float* th = thr + b * NN;
  __shared__ float A[64][65];
  int t = threadIdx.x;
  int i0 = I * 64, j0 = J * 64;
  float areg[16];
#pragma unroll
  for (int e = 0; e < 16; ++e) {
    int lin = t + e * 256;
    int i = lin >> 6, j = lin & 63;
    areg[e] = Mb[(size_t)(i0 + i) * NN + j0 + j];
  }
#pragma unroll
  for (int e = 0; e < 16; ++e) {
    int lin = t + e * 256;
    int i = lin >> 6, j = lin & 63;
    float a = areg[e];
    float v = a * ((a >= th[i0 + i] ? 1.f : 0.f) + (a >= th[j0 + j] ? 1.f : 0.f));
    A[i][j] = v;
  }
  __syncthreads();
  {
    int i = t >> 2, seg = (t & 3) * 16;
    float v[16];
#pragma unroll
    for (int q = 0; q < 4; ++q)
      *reinterpret_cast<float4*>(&v[q * 4]) = *reinterpret_cast<float4*>(&A[i][seg + q * 4]);
    unsigned int pk[8];
#pragma unroll
    for (int q = 0; q < 8; ++q) pk[q] = pack2(v[2 * q], v[2 * q + 1]);
    size_t ub = 2 * (size_t)(i0 + i) * NN + 2 * (size_t)j0 + seg;
    *reinterpret_cast<int4*>(&Mus[ub])     = *reinterpret_cast<int4*>(&pk[0]);
    *reinterpret_cast<int4*>(&Mus[ub + 8]) = *reinterpret_cast<int4*>(&pk[4]);
  }
  if (I != J) {   // As is symmetric: mirror footprint gets A^T
    int j = t >> 2, seg = (t & 3) * 16;
    float v[16];
#pragma unroll
    for (int e = 0; e < 16; ++e) v[e] = A[seg + e][j];
    unsigned int pk[8];
#pragma unroll
    for (int q = 0; q < 8; ++q) pk[q] = pack2(v[2 * q], v[2 * q + 1]);
    size_t ub = 2 * (size_t)(j0 + j) * NN + 2 * (size_t)i0 + seg;
    *reinterpret_cast<int4*>(&Mus[ub])     = *reinterpret_cast<int4*>(&pk[0]);
    *reinterpret_cast<int4*>(&Mus[ub + 8]) = *reinterpret_cast<int4*>(&pk[4]);
  }
  if (t < 64) {
    float s = 0.f;
#pragma unroll
    for (int j = 0; j < 64; ++j) s += A[t][j];
    atomicAdd(&dsum[b * NN + i0 + t], s);
  } else if (t < 128 && I != J) {
    int j = t - 64;
    float s = 0.f;
#pragma unroll
    for (int i = 0; i < 64; ++i) s += A[i][j];
    atomicAdd(&dsum[b * NN + j0 + j], s);
  }
}

// ---------------------------------------------------------------------------
// K6: d = (d + 1e-10)^-0.5
// ---------------------------------------------------------------------------
__global__ void k_fin_d(float* __restrict__ d) {
  int g = blockIdx.x * 256 + threadIdx.x;
  if (g < BB * NN) d[g] = 1.f / sqrtf(d[g] + 1e-10f);
}

// ---------------------------------------------------------------------------
// K7: ybh[b][c][n] = bf16(d1[b][n] * pred[b][c][n]), zero-padded to 32 classes
// ---------------------------------------------------------------------------
__global__ void k_make_yb(const float* __restrict__ pred, const float* __restrict__ d1,
                          unsigned short* __restrict__ ybh) {
  int g = blockIdx.x * 256 + threadIdx.x;   // BB*32*NN/4 threads
  int idx = g * 4;
  int b = idx / (32 * NN);
  int c = (idx / NN) & 31;
  int n = idx & (NN - 1);
  ushort4 o = make_ushort4(0, 0, 0, 0);
  if (c < CC) {
    float4 p = *reinterpret_cast<const float4*>(&pred[((size_t)b * CC + c) * NN + n]);
    const float* dd = d1 + b * NN + n;
    o.x = f2b(p.x * dd[0]); o.y = f2b(p.y * dd[1]);
    o.z = f2b(p.z * dd[2]); o.w = f2b(p.w * dd[3]);
  }
  *reinterpret_cast<ushort4*>(&ybh[idx]) = o;
}

// ---------------------------------------------------------------------------
// K8: p2 via MFMA.  GEMM: M=n (64-tile), N=c (32 padded), K=m (4096).
// ---------------------------------------------------------------------------
__global__ __launch_bounds__(256) void k_p2_mfma(
    const float* __restrict__ M, const unsigned short* __restrict__ ybh,
    const float* __restrict__ d1, float* __restrict__ p2b) {
  int b = blockIdx.y;
  int n0 = blockIdx.x * 64;
  const unsigned short* Mus = (const unsigned short*)(M + (size_t)b * NN * NN);
  const unsigned short* Y = ybh + (size_t)b * 32 * NN;
  __shared__ unsigned short As[64][72];
  __shared__ unsigned short Ys[32][72];
  int t = threadIdx.x;
  int wave = t >> 6, lane = t & 63;
  int wn = (wave & 1) * 32;
  int wc = (wave >> 1) * 16;
  int lrow = lane & 15, quad = lane >> 4;
  f32x4 acc[2] = {{0.f,0.f,0.f,0.f},{0.f,0.f,0.f,0.f}};
  int sr = t >> 3, scc = (t & 7) * 8;
  for (int m0 = 0; m0 < NN; m0 += 64) {
#pragma unroll
    for (int e = 0; e < 2; ++e) {
      int rr = sr + e * 32;
      *reinterpret_cast<int4*>(&As[rr][scc]) =
          *reinterpret_cast<const int4*>(&Mus[2 * (size_t)(n0 + rr) * NN + 2 * (size_t)m0 + scc]);
    }
    *reinterpret_cast<int4*>(&Ys[sr][scc]) =
        *reinterpret_cast<const int4*>(&Y[(size_t)sr * NN + m0 + scc]);
    __syncthreads();
#pragma unroll
    for (int kc = 0; kc < 2; ++kc) {
      int ko = kc * 32 + quad * 8;
      bf16x8 bfr = *reinterpret_cast<const bf16x8*>(&Ys[wc + lrow][ko]);
#pragma unroll
      for (int i = 0; i < 2; ++i) {
        bf16x8 af = *reinterpret_cast<const bf16x8*>(&As[wn + i * 16 + lrow][ko]);
        acc[i] = __builtin_amdgcn_mfma_f32_16x16x32_bf16(af, bfr, acc[i], 0, 0, 0);
      }
    }
    __syncthreads();
  }
  int c = wc + lrow;
  if (c < CC) {
#pragma unroll
    for (int i = 0; i < 2; ++i) {
#pragma unroll
      for (int reg = 0; reg < 4; ++reg) {
        int n = n0 + wn + i * 16 + quad * 4 + reg;
        p2b[((size_t)b * NN + n) * CC + c] = d1[b * NN + n] * acc[i][reg];
      }
    }
  }
}

// ---------------------------------------------------------------------------
// K9: fused blend + 19x19 conv x2 -> pred_out, then softmax + cosine-normalize
// ---------------------------------------------------------------------------
__global__ __launch_bounds__(256) void k_pred_head(const float* __restrict__ pred,
    const float* __restrict__ p2b, const float* __restrict__ maskb,
    const float* __restrict__ w1, const float* __restrict__ b1,
    const float* __restrict__ w2, const float* __restrict__ b2,
    float* __restrict__ out, float* __restrict__ spnT) {
  __shared__ float sw1[CC * CC], sw2[CC * CC], sb1[CC], sb2[CC];
  int t = threadIdx.x;
  for (int i = t; i < CC * CC; i += 256) { sw1[i] = w1[i]; sw2[i] = w2[i]; }
  if (t < CC) { sb1[t] = b1[t]; sb2[t] = b2[t]; }
  __syncthreads();
  int g = blockIdx.x * 256 + t;
  int b = g >> 12, n = g & (NN - 1);
  float m = maskb[g];
  float ca = (m > 0.5f) ? 0.2f : 0.8f;
  float cb = (m > 0.5f) ? 0.8f : 0.2f;
  const float* P = pred + (size_t)b * CC * NN + n;
  const float* Q = p2b + (size_t)g * CC;
  float p3[CC];
#pragma unroll
  for (int c = 0; c < CC; ++c) p3[c] = ca * Q[c] + cb * P[(size_t)c * NN];
  float midv[CC];
#pragma unroll
  for (int o = 0; o < CC; ++o) {
    float s = sb1[o];
#pragma unroll
    for (int c = 0; c < CC; ++c) s += sw1[o * CC + c] * p3[c];
    midv[o] = s;
  }
  float ov[CC];
  float mx = -1e30f;
#pragma unroll
  for (int o = 0; o < CC; ++o) {
    float s = sb2[o];
#pragma unroll
    for (int c = 0; c < CC; ++c) s += sw2[o * CC + c] * midv[c];
    ov[o] = s;
    out[(size_t)b * CC * NN + (size_t)o * NN + n] = s;
    mx = fmaxf(mx, s);
  }
  float se = 0.f;
  float e[CC];
#pragma unroll
  for (int o = 0; o < CC; ++o) { e[o] = expf(ov[o] - mx); se += e[o]; }
  float inv = 1.f / se;
  float nrm = 0.f;
#pragma unroll
  for (int o = 0; o < CC; ++o) { float sp = e[o] * inv; e[o] = sp; nrm += sp * sp; }
  float rn = 1.f / (sqrtf(nrm) + 1e-9f);
#pragma unroll
  for (int o = 0; o < CC; ++o) spnT[(size_t)b * CC * NN + (size_t)o * NN + n] = e[o] * rn;
}

// ---------------------------------------------------------------------------
// K10: aff_f = bitmask ? clamp(Gram(spn),0) : 0   (K=19), writes bf16.
// ---------------------------------------------------------------------------
__global__ __launch_bounds__(256) void k_gram2(const float* __restrict__ spnT,
    const unsigned int* __restrict__ bits, unsigned short* __restrict__ Mh) {
  int L = blockIdx.x;          // 0..2079 triangular (64 tiles/dim)
  int b = blockIdx.y;
  int I = 0;
  while (L >= 64 - I) { L -= 64 - I; ++I; }
  int J = I + L;
  const float* X = spnT + (size_t)b * CC * NN;
  unsigned short* Mb = Mh + (size_t)b * NN * NN;
  __shared__ float sA[CC][64], sB[CC][64];
  __shared__ unsigned int bI[64], bJ[64];
  __shared__ float tr[64][65];
  int t = threadIdx.x;
  int r = t >> 4, c = t & 15;
  int i0 = I * 64, j0 = J * 64;
  for (int e = t; e < CC * 64; e += 256) {
    int k = e >> 6, col = e & 63;
    sA[k][col] = X[(size_t)k * NN + i0 + col];
    sB[k][col] = X[(size_t)k * NN + j0 + col];
  }
  if (t < 64) bI[t] = bits[b * NN + i0 + t];
  else if (t < 128) bJ[t - 64] = bits[b * NN + j0 + t - 64];
  __syncthreads();
  float acc[4][4] = {};
#pragma unroll
  for (int k = 0; k < CC; ++k) {
    float av[4], bv[4];
#pragma unroll
    for (int i = 0; i < 4; ++i) av[i] = sA[k][r * 4 + i];
#pragma unroll
    for (int j = 0; j < 4; ++j) bv[j] = sB[k][c * 4 + j];
#pragma unroll
    for (int i = 0; i < 4; ++i) {
#pragma unroll
      for (int j = 0; j < 4; ++j) acc[i][j] += av[i] * bv[j];
    }
  }
#pragma unroll
  for (int i = 0; i < 4; ++i) {
#pragma unroll
    for (int j = 0; j < 4; ++j) {
      bool keep = (bI[r * 4 + i] & bJ[c * 4 + j]) != 0u;
      acc[i][j] = keep ? fmaxf(acc[i][j], 0.f) : 0.f;
    }
    ushort4 v;
    v.x = f2b(acc[i][0]); v.y = f2b(acc[i][1]); v.z = f2b(acc[i][2]); v.w = f2b(acc[i][3]);
    *reinterpret_cast<ushort4*>(&Mb[(size_t)(i0 + r * 4 + i) * NN + j0 + c * 4]) = v;
  }
  if (I != J) {
#pragma unroll
    for (int i = 0; i < 4; ++i) {
#pragma unroll
      for (int j = 0; j < 4; ++j) tr[r * 4 + i][c * 4 + j] = acc[i][j];
    }
    __syncthreads();
#pragma unroll
    for (int e = 0; e < 16; ++e) {
      int lin = t + e * 256;
      int jr = lin >> 6, ic = lin & 63;
      Mb[(size_t)(j0 + jr) * NN + i0 + ic] = f2b(tr[ic][jr]);
    }
  }
}

// ---------------------------------------------------------------------------
// K11: d2[n] = (row_sum(aff_f bf16) + 1e-10)^-0.5
// ---------------------------------------------------------------------------
__global__ __launch_bounds__(256) void k_rowsum2h(const unsigned short* __restrict__ Mh,
                                                  float* __restrict__ d2) {
  int b = blockIdx.y, n = blockIdx.x;
  const unsigned short* row = Mh + (size_t)b * NN * NN + (size_t)n * NN;
  int t = threadIdx.x;
  float s = 0.f;
#pragma unroll
  for (int i = 0; i < 8; ++i) {
    unsigned int u = *reinterpret_cast<const unsigned int*>(&row[(i * 256 + t) * 2]);
    s += __uint_as_float(u << 16) + __uint_as_float(u & 0xffff0000u);
  }
  for (int off = 32; off > 0; off >>= 1) s += __shfl_down(s, off);
  __shared__ float p4[4];
  int wid = t >> 6, lane = t & 63;
  if (lane == 0) p4[wid] = s;
  __syncthreads();
  if (t == 0) d2[b * NN + n] = 1.f / sqrtf(p4[0] + p4[1] + p4[2] + p4[3] + 1e-10f);
}

// ---------------------------------------------------------------------------
// K12a: zb[b][d][m] = bf16(feat[b][d][m] * d2[b][m])
// ---------------------------------------------------------------------------
__global__ void k_make_z(const float* __restrict__ feat, const float* __restrict__ d2,
                         unsigned short* __restrict__ zb) {
  int g = blockIdx.x * 256 + threadIdx.x;   // BB*DD*NN/4 threads
  int idx = g * 4;
  int b = idx / (DD * NN);
  int m = idx & (NN - 1);
  float4 f = *reinterpret_cast<const float4*>(&feat[idx]);
  const float* dd = d2 + b * NN + m;
  ushort4 o;
  o.x = f2b(f.x * dd[0]); o.y = f2b(f.y * dd[1]);
  o.z = f2b(f.z * dd[2]); o.w = f2b(f.w * dd[3]);
  *reinterpret_cast<ushort4*>(&zb[idx]) = o;
}

// K12b: convert projection weights to bf16
__global__ void k_prep_w(const float* __restrict__ w1, const float* __restrict__ w2,
                         unsigned short* __restrict__ wb1, unsigned short* __restrict__ wb2) {
  int g = blockIdx.x * 256 + threadIdx.x;   // DD*DD threads
  wb1[g] = f2b(w1[g]);
  wb2[g] = f2b(w2[g]);
}

// ---------------------------------------------------------------------------
// K13: new_feat via MFMA with split-K x4.  GEMM: M=d(64), N=n(64), K=1024.
// ---------------------------------------------------------------------------
__global__ __launch_bounds__(256) void k_newfeat_mfma(
    const unsigned short* __restrict__ Mh, const unsigned short* __restrict__ zb,
    float* __restrict__ nfp) {
  int zz = blockIdx.z;                 // b*KSPLIT + ks
  int b = zz / KSPLIT, ks = zz % KSPLIT;
  int nblk = blockIdx.x;   // 64
  int dblk = blockIdx.y;   // 4
  const int KLEN = NN / KSPLIT;        // 1024
  const unsigned short* A = zb + (size_t)b * DD * NN + (size_t)(dblk * 64) * NN + ks * KLEN;
  const unsigned short* Bm = Mh + (size_t)b * NN * NN + (size_t)(nblk * 64) * NN + ks * KLEN;
  __shared__ unsigned short As[64][72];
  __shared__ unsigned short Bs[64][72];
  int t = threadIdx.x;
  int wave = t >> 6, lane = t & 63;
  int wd = (wave & 1) * 32, wn = (wave >> 1) * 32;
  int lrow = lane & 15, quad = lane >> 4;
  f32x4 acc[2][2] = {{{0.f,0.f,0.f,0.f},{0.f,0.f,0.f,0.f}},{{0.f,0.f,0.f,0.f},{0.f,0.f,0.f,0.f}}};
  int sr = t >> 3, sc = (t & 7) * 8;
  for (int m0 = 0; m0 < KLEN; m0 += 64) {
#pragma unroll
    for (int e = 0; e < 2; ++e) {
      int rr = sr + e * 32;
      *reinterpret_cast<int4*>(&As[rr][sc]) =
          *reinterpret_cast<const int4*>(&A[(size_t)rr * NN + m0 + sc]);
      *reinterpret_cast<int4*>(&Bs[rr][sc]) =
          *reinterpret_cast<const int4*>(&Bm[(size_t)rr * NN + m0 + sc]);
    }
    __syncthreads();
#pragma unroll
    for (int kc = 0; kc < 2; ++kc) {
      int ko = kc * 32 + quad * 8;
      bf16x8 af[2], bfr[2];
#pragma unroll
      for (int i = 0; i < 2; ++i) {
        af[i]  = *reinterpret_cast<const bf16x8*>(&As[wd + i * 16 + lrow][ko]);
        bfr[i] = *reinterpret_cast<const bf16x8*>(&Bs[wn + i * 16 + lrow][ko]);
      }
#pragma unroll
      for (int i = 0; i < 2; ++i)
#pragma unroll
        for (int j = 0; j < 2; ++j)
          acc[i][j] = __builtin_amdgcn_mfma_f32_16x16x32_bf16(af[i], bfr[j], acc[i][j], 0, 0, 0);
    }
    __syncthreads();
  }
#pragma unroll
  for (int j = 0; j < 2; ++j) {
    int n = nblk * 64 + wn + j * 16 + lrow;
#pragma unroll
    for (int i = 0; i < 2; ++i) {
      int d = dblk * 64 + wd + i * 16 + quad * 4;
      float4 v = make_float4(acc[i][j].x, acc[i][j].y, acc[i][j].z, acc[i][j].w);
      *reinterpret_cast<float4*>(&nfp[((size_t)zz * NN + n) * DD + d]) = v;
    }
  }
}

// ---------------------------------------------------------------------------
// K13b: reduce split-K partials, scale by d2, emit bf16 nfh[b][n][d]
// ---------------------------------------------------------------------------
__global__ void k_nf_reduce(const float* __restrict__ nfp, const float* __restrict__ d2,
                            unsigned short* __restrict__ nfh) {
  int g = blockIdx.x * 256 + threadIdx.x;   // BB*NN*DD/4 threads
  int idx = g * 4;
  int b = idx / (NN * DD);
  int n = (idx / DD) & (NN - 1);
  size_t base = (size_t)idx + (size_t)b * (KSPLIT - 1) * NN * DD;
  float4 s = make_float4(0.f, 0.f, 0.f, 0.f);
#pragma unroll
  for (int ks = 0; ks < KSPLIT; ++ks) {
    float4 v = *reinterpret_cast<const float4*>(&nfp[base + (size_t)ks * NN * DD]);
    s.x += v.x; s.y += v.y; s.z += v.z; s.w += v.w;
  }
  float sc = d2[b * NN + n];
  ushort4 o;
  o.x = f2b(s.x * sc); o.y = f2b(s.y * sc); o.z = f2b(s.z * sc); o.w = f2b(s.w * sc);
  *reinterpret_cast<ushort4*>(&nfh[idx]) = o;
}

// ---------------------------------------------------------------------------
// K14: conv1 via MFMA. GEMM: M=n, N=o1, K=d.
// ---------------------------------------------------------------------------
__global__ __launch_bounds__(256) void k_conv1_mfma(
    const unsigned short* __restrict__ nfh, const unsigned short* __restrict__ wb1,
    const float* __restrict__ b1, unsigned short* __restrict__ midh) {
  int b = blockIdx.z;
  int nblk = blockIdx.x;   // 64
  int oblk = blockIdx.y;   // 4
  int n0 = nblk * 64, o0 = oblk * 64;
  __shared__ unsigned short As[64][72];
  __shared__ unsigned short Bs[64][72];
  int t = threadIdx.x;
  int wave = t >> 6, lane = t & 63;
  int wn = (wave & 1) * 32, wo = (wave >> 1) * 32;
  int lrow = lane & 15, quad = lane >> 4;
  f32x4 acc[2][2] = {{{0.f,0.f,0.f,0.f},{0.f,0.f,0.f,0.f}},{{0.f,0.f,0.f,0.f},{0.f,0.f,0.f,0.f}}};
  int sr = t >> 3, sc = (t & 7) * 8;
  for (int d0 = 0; d0 < DD; d0 += 64) {
#pragma unroll
    for (int e = 0; e < 2; ++e) {
      int rr = sr + e * 32;
      *reinterpret_cast<int4*>(&As[rr][sc]) =
          *reinterpret_cast<const int4*>(&nfh[((size_t)b * NN + n0 + rr) * DD + d0 + sc]);
      *reinterpret_cast<int4*>(&Bs[rr][sc]) =
          *reinterpret_cast<const int4*>(&wb1[(size_t)(o0 + rr) * DD + d0 + sc]);
    }
    __syncthreads();
#pragma unroll
    for (int kc = 0; kc < 2; ++kc) {
      int ko = kc * 32 + quad * 8;
      bf16x8 af[2], bfr[2];
#pragma unroll
      for (int i = 0; i < 2; ++i) {
        af[i]  = *reinterpret_cast<const bf16x8*>(&As[wn + i * 16 + lrow][ko]);
        bfr[i] = *reinterpret_cast<const bf16x8*>(&Bs[wo + i * 16 + lrow][ko]);
      }
#pragma unroll
      for (int i = 0; i < 2; ++i)
#pragma unroll
        for (int j = 0; j < 2; ++j)
          acc[i][j] = __builtin_amdgcn_mfma_f32_16x16x32_bf16(af[i], bfr[j], acc[i][j], 0, 0, 0);
    }
    __syncthreads();
  }
#pragma unroll
  for (int j = 0; j < 2; ++j) {
    int o = o0 + wo + j * 16 + lrow;
    float bias = b1[o];
#pragma unroll
    for (int i = 0; i < 2; ++i) {
      int nb = n0 + wn + i * 16 + quad * 4;
      ushort4 v;
      v.x = f2b(fmaxf(acc[i][j].x + bias, 0.f));
      v.y = f2b(fmaxf(acc[i][j].y + bias, 0.f));
      v.z = f2b(fmaxf(acc[i][j].z + bias, 0.f));
      v.w = f2b(fmaxf(acc[i][j].w + bias, 0.f));
      *reinterpret_cast<ushort4*>(&midh[((size_t)b * DD + o) * NN + nb]) = v;
    }
  }
}

// ---------------------------------------------------------------------------
// K15: conv2 via MFMA. GEMM: M=n, N=o2, K=o1.
// ---------------------------------------------------------------------------
__global__ __launch_bounds__(256) void k_conv2_mfma(
    const unsigned short* __restrict__ midh, const unsigned short* __restrict__ wb2,
    const float* __restrict__ b2, float* __restrict__ outp) {
  int b = blockIdx.z;
  int nblk = blockIdx.x;   // 64
  int oblk = blockIdx.y;   // 4
  int n0 = nblk * 64, o0 = oblk * 64;
  __shared__ unsigned short As[64][72];
  __shared__ unsigned short Bs[64][72];
  int t = threadIdx.x;
  int wave = t >> 6, lane = t & 63;
  int wn = (wave & 1) * 32, wo = (wave >> 1) * 32;
  int lrow = lane & 15, quad = lane >> 4;
  f32x4 acc[2][2] = {{{0.f,0.f,0.f,0.f},{0.f,0.f,0.f,0.f}},{{0.f,0.f,0.f,0.f},{0.f,0.f,0.f,0.f}}};
  int sr = t >> 3, sc = (t & 7) * 8;
  for (int d0 = 0; d0 < DD; d0 += 64) {
#pragma unroll
    for (int e = 0; e < 2; ++e) {
      int rr = sr + e * 32;
      *reinterpret_cast<int4*>(&Bs[rr][sc]) =
          *reinterpret_cast<const int4*>(&wb2[(size_t)(o0 + rr) * DD + d0 + sc]);
      unsigned short v[8];
      *reinterpret_cast<int4*>(v) =
          *reinterpret_cast<const int4*>(&midh[((size_t)b * DD + d0 + rr) * NN + n0 + sc]);
#pragma unroll
      for (int j = 0; j < 8; ++j) As[sc + j][rr] = v[j];
    }
    __syncthreads();
#pragma unroll
    for (int kc = 0; kc < 2; ++kc) {
      int ko = kc * 32 + quad * 8;
      bf16x8 af[2], bfr[2];
#pragma unroll
      for (int i = 0; i < 2; ++i) {
        af[i]  = *reinterpret_cast<const bf16x8*>(&As[wn + i * 16 + lrow][ko]);
        bfr[i] = *reinterpret_cast<const bf16x8*>(&Bs[wo + i * 16 + lrow][ko]);
      }
#pragma unroll
      for (int i = 0; i < 2; ++i)
#pragma unroll
        for (int j = 0; j < 2; ++j)
          acc[i][j] = __builtin_amdgcn_mfma_f32_16x16x32_bf16(af[i], bfr[j], acc[i][j], 0, 0, 0);
    }
    __syncthreads();
  }
#pragma unroll
  for (int j = 0; j < 2; ++j) {
    int o = o0 + wo + j * 16 + lrow;
    float bias = b2[o];
#pragma unroll
    for (int i = 0; i < 2; ++i) {
      int nb = n0 + wn + i * 16 + quad * 4;
      float4 v = make_float4(acc[i][j].x + bias, acc[i][j].y + bias,
                             acc[i][j].z + bias, acc[i][j].w + bias);
      *reinterpret_cast<float4*>(&outp[((size_t)b * DD + o) * NN + nb]) = v;
    }
  }
}

// ---------------------------------------------------------------------------
extern "C" void kernel_launch(void* const* d_in, const int* in_sizes, int n_in,
                              void* d_out, int out_size, void* d_ws, size_t ws_size,
                              hipStream_t stream) {
  (void)in_sizes; (void)n_in; (void)out_size; (void)ws_size;
  const float* pred   = (const float*)d_in[0];
  const float* feat   = (const float*)d_in[1];
  const float* w_cls1 = (const float*)d_in[2];
  const float* b_cls1 = (const float*)d_in[3];
  const float* w_cls2 = (const float*)d_in[4];
  const float* b_cls2 = (const float*)d_in[5];
  const float* w_pro1 = (const float*)d_in[6];
  const float* b_pro1 = (const float*)d_in[7];
  const float* w_pro2 = (const float*)d_in[8];
  const float* b_pro2 = (const float*)d_in[9];
  const float* cw     = (const float*)d_in[10];
  float* out = (float*)d_out;

  // workspace layout
  float* Mbuf = (float*)d_ws;                               // B*N*N fp32 (aff1 / packed-bf16 As / bf16 aff_f)
  float* spnT = Mbuf + (size_t)BB * NN * NN;
  float* p2b  = spnT + (size_t)BB * CC * NN;
  float* thr  = p2b + (size_t)BB * NN * CC;
  float* dsum = thr + BB * NN;
  float* d2s  = dsum + BB * NN;
  float* maskb = d2s + BB * NN;
  unsigned int* ohbits = (unsigned int*)(maskb + BB * NN);
  unsigned short* xh   = (unsigned short*)(ohbits + BB * NN);  // B*N*D fp16 hi
  unsigned short* xl   = xh + (size_t)BB * NN * DD;            // B*N*D fp16 lo*2^11
  unsigned short* nfh  = xl + (size_t)BB * NN * DD;            // B*N*D bf16
  unsigned short* midh = nfh + (size_t)BB * NN * DD;           // B*D*N bf16
  unsigned short* zb   = midh + (size_t)BB * DD * NN;          // B*D*N bf16
  unsigned short* wb1  = zb + (size_t)BB * DD * NN;            // D*D bf16
  unsigned short* wb2  = wb1 + (size_t)DD * DD;                // D*D bf16
  unsigned short* ybh  = wb2 + (size_t)DD * DD;                // B*32*N bf16 (padded y)
  unsigned short* Mh   = (unsigned short*)Mbuf;
  // split-K partials alias the upper half of Mbuf (dead after k_p2)
  float* nfp = (float*)(Mh + (size_t)BB * NN * NN);            // KSPLIT*B*N*D fp32 = 32 MB

  hipMemsetAsync(dsum, 0, sizeof(float) * BB * NN, stream);
  hipMemsetAsync(ohbits, 0, sizeof(unsigned int) * BB * NN, stream);

  // --- pred branch ---
  k_mask_bits<<<BB * NN / 256, 256, 0, stream>>>(pred, cw, maskb, ohbits);
  k_norm_feat<<<BB * NN / 64, 64, 0, stream>>>(feat, xh, xl);
  k_gram1<<<dim3(528, BB), 256, 0, stream>>>(xh, xl, Mbuf);
  k_topk<<<dim3(NN / 4, BB), 256, 0, stream>>>(Mbuf, thr);
  k_symm<<<dim3(2080, BB), 256, 0, stream>>>(Mbuf, thr, dsum);
  k_fin_d<<<BB * NN / 256, 256, 0, stream>>>(dsum);
  k_make_yb<<<BB * 32 * NN / 4 / 256, 256, 0, stream>>>(pred, dsum, ybh);
  k_p2_mfma<<<dim3(NN / 64, BB), 256, 0, stream>>>(Mbuf, ybh, dsum, p2b);
  k_pred_head<<<BB * NN / 256, 256, 0, stream>>>(pred, p2b, maskb, w_cls1, b_cls1,
                                                 w_cls2, b_cls2, out, spnT);
  // --- feat branch (bf16 MFMA) ---
  k_gram2<<<dim3(2080, BB), 256, 0, stream>>>(spnT, ohbits, Mh);
  k_rowsum2h<<<dim3(NN, BB), 256, 0, stream>>>(Mh, d2s);
  k_make_z<<<BB * DD * NN / 4 / 256, 256, 0, stream>>>(feat, d2s, zb);
  k_prep_w<<<DD * DD / 256, 256, 0, stream>>>(w_pro1, w_pro2, wb1, wb2);
  k_newfeat_mfma<<<dim3(64, 4, BB * KSPLIT), 256, 0, stream>>>(Mh, zb, nfp);
  k_nf_reduce<<<BB * NN * DD / 4 / 256, 256, 0, stream>>>(nfp, d2s, nfh);
  k_conv1_mfma<<<dim3(64, 4, BB), 256, 0, stream>>>(nfh, wb1, b_pro1, midh);
  k_conv2_mfma<<<dim3(64, 4, BB), 256, 0, stream>>>(midh, wb2, b_pro2,
                                                    out + (size_t)BB * CC * NN);
}